// Round 2
// baseline (751.714 us; speedup 1.0000x reference)
//
#include <hip/hip_runtime.h>
#include <hip/hip_bf16.h>

#define NN 16384     // nodes
#define FD 512       // feature dim
#define EMB 128      // embed_dim (dense1)
#define OD 64        // out_dim
#define NE 524288    // edges
#define NTOT (NE + NN)  // edges + self loops = 540672

typedef __bf16 bf16x8 __attribute__((ext_vector_type(8)));
typedef float f32x4 __attribute__((ext_vector_type(4)));

// ---------------- zero scratch (denom, out_gat, xtw are contiguous) --------
__global__ void k_zero(float* __restrict__ p, int n) {
    int i = blockIdx.x * 256 + threadIdx.x;
    if (i < n) p[i] = 0.f;
}

// ---------------- h = x @ W_gat ; a_src = h@att_src ; a_dst = h@att_dst ----
__global__ __launch_bounds__(256) void k_gath(
    const float* __restrict__ x, const float* __restrict__ Wg,
    const float* __restrict__ att_s, const float* __restrict__ att_d,
    float* __restrict__ h, float* __restrict__ a_src, float* __restrict__ a_dst) {
    __shared__ float xs[16 * FD];                      // 32 KB
    int r0 = blockIdx.x * 16;
    const float4* xin = reinterpret_cast<const float4*>(x + (size_t)r0 * FD);
    float4* xls = reinterpret_cast<float4*>(xs);
#pragma unroll
    for (int j = 0; j < 8; ++j) xls[threadIdx.x + 256 * j] = xin[threadIdx.x + 256 * j];
    __syncthreads();
    int c = threadIdx.x & 63;
    int rg = threadIdx.x >> 6;                          // wave id: 4 rows each
    const float* xrow = xs + rg * 4 * FD;
    float acc0 = 0.f, acc1 = 0.f, acc2 = 0.f, acc3 = 0.f;
    for (int k = 0; k < FD; ++k) {
        float w = Wg[k * OD + c];
        acc0 += xrow[k] * w;
        acc1 += xrow[FD + k] * w;
        acc2 += xrow[2 * FD + k] * w;
        acc3 += xrow[3 * FD + k] * w;
    }
    float hv[4] = {acc0, acc1, acc2, acc3};
    float as = att_s[c], ad = att_d[c];
#pragma unroll
    for (int i = 0; i < 4; ++i) {
        int r = r0 + rg * 4 + i;
        h[(size_t)r * OD + c] = hv[i];
        float vs = hv[i] * as, vd = hv[i] * ad;
#pragma unroll
        for (int off = 32; off >= 1; off >>= 1) {
            vs += __shfl_xor(vs, off, 64);
            vd += __shfl_xor(vd, off, 64);
        }
        if (c == 0) { a_src[r] = vs; a_dst[r] = vd; }
    }
}

// ---------------- edge pass 1: p = exp(leaky(e)), denom += p ---------------
__global__ void k_edgep(const int* __restrict__ ei, const float* __restrict__ a_src,
                        const float* __restrict__ a_dst, float* __restrict__ p,
                        float* __restrict__ denom) {
    int i = blockIdx.x * 256 + threadIdx.x;
    if (i >= NTOT) return;
    int s, d;
    if (i < NE) { s = ei[i]; d = ei[NE + i]; } else { s = d = i - NE; }
    float e = a_src[s] + a_dst[d];
    e = e > 0.f ? e : 0.5f * e;               // GAT negative_slope = 0.5
    float pv = __expf(e);                     // max-shift cancels in alpha
    p[i] = pv;
    atomicAdd(denom + d, pv);
}

// ---------------- edge pass 2: out[d] += (p/denom[d]) * h[s] ---------------
__global__ __launch_bounds__(256) void k_agg(const int* __restrict__ ei,
                                             const float* __restrict__ p,
                                             const float* __restrict__ denom,
                                             const float* __restrict__ h,
                                             float* __restrict__ outg) {
    int wv = blockIdx.x * 4 + (threadIdx.x >> 6);   // one wave per edge
    if (wv >= NTOT) return;
    int lane = threadIdx.x & 63;
    int s, d;
    if (wv < NE) { s = ei[wv]; d = ei[NE + wv]; } else { s = d = wv - NE; }
    float alpha = p[wv] / denom[d];
    atomicAdd(outg + (size_t)d * OD + lane, alpha * h[(size_t)s * OD + lane]);
}

// ---------------- embed = leaky_relu(out_gat + b_gat, 0.01) -> bf16 --------
__global__ void k_embed(const float* __restrict__ outg, const float* __restrict__ bg,
                        __hip_bfloat16* __restrict__ ebf) {
    int i = blockIdx.x * 256 + threadIdx.x;          // NN*OD total
    float v = outg[i] + bg[i & 63];
    v = v > 0.f ? v : 0.01f * v;
    ebf[i] = __float2bfloat16(v);
}

// ---------------- xtw[f][e] = sum_n x[n][f] * W1[n][e]  (partials+atomics) -
__global__ __launch_bounds__(256) void k_xtw(const float* __restrict__ x,
                                             const float* __restrict__ W1,
                                             float* __restrict__ xtw) {
    __shared__ float xs[4][64];
    __shared__ float ws[4][EMB];
    int fb = blockIdx.x & 7;       // 8 f-tiles of 64
    int nc = blockIdx.x >> 3;      // 32 n-chunks of 512
    int f0 = fb * 64;
    int nb = nc * 512;
    int t = threadIdx.x;
    int eb = (t & 15) * 8;         // 8 e per thread
    int fbase = (t >> 4) * 4;      // 4 f per thread
    float acc[4][8] = {};
    for (int n4 = 0; n4 < 512; n4 += 4) {
        { int nn = t >> 6, ff = t & 63;
          xs[nn][ff] = x[(size_t)(nb + n4 + nn) * FD + f0 + ff]; }
#pragma unroll
        for (int j = 0; j < 2; ++j) {
            int idx = t + j * 256;
            ws[idx >> 7][idx & 127] = W1[(size_t)(nb + n4 + (idx >> 7)) * EMB + (idx & 127)];
        }
        __syncthreads();
#pragma unroll
        for (int nn = 0; nn < 4; ++nn) {
            float xv[4], wv[8];
#pragma unroll
            for (int i = 0; i < 4; ++i) xv[i] = xs[nn][fbase + i];
#pragma unroll
            for (int j = 0; j < 8; ++j) wv[j] = ws[nn][eb + j];
#pragma unroll
            for (int i = 0; i < 4; ++i)
#pragma unroll
                for (int j = 0; j < 8; ++j) acc[i][j] += xv[i] * wv[j];
        }
        __syncthreads();
    }
#pragma unroll
    for (int i = 0; i < 4; ++i)
#pragma unroll
        for (int j = 0; j < 8; ++j)
            atomicAdd(xtw + (size_t)(f0 + fbase + i) * EMB + eb + j, acc[i][j]);
}

// ---------------- h2 = relu(xtw + b1) @ W2 + b2 -> bf16 rows ---------------
__global__ __launch_bounds__(256) void k_h2(const float* __restrict__ xtw,
                                            const float* __restrict__ b1,
                                            const float* __restrict__ W2,
                                            const float* __restrict__ b2,
                                            __hip_bfloat16* __restrict__ h2bf) {
    int f = blockIdx.x * 4 + (threadIdx.x >> 6);
    int c = threadIdx.x & 63;
    float acc = b2[c];
    const float* row = xtw + (size_t)f * EMB;
    for (int e = 0; e < EMB; ++e) {
        float hv = row[e] + b1[e];
        hv = hv > 0.f ? hv : 0.f;
        acc += hv * W2[e * OD + c];
    }
    h2bf[(size_t)f * OD + c] = __float2bfloat16(acc);
}

// ---------------- out[i][j] = act( A_rows[i] . B_rows[j] ), K = 64 ---------
// MFMA 16x16x32 bf16. A-frag: lane l holds A[l&15][ (l>>4)*8 + i ] (16B row load)
// B-frag: lane l holds B[k][l&15] = Brow[l&15][k], same 16B row load.
// D: col = lane&15, row = (lane>>4)*4 + reg  (verified layout).
template <bool SIG>
__global__ __launch_bounds__(256) void k_mm(const __hip_bfloat16* __restrict__ A,
                                            const __hip_bfloat16* __restrict__ B,
                                            float* __restrict__ out, int ldo) {
    int i0 = blockIdx.x * 128;       // 128 rows per block (4 waves x 32)
    int j0 = blockIdx.y * 64;        // 64 cols per block
    int w = threadIdx.x >> 6;
    int l = threadIdx.x & 63;
    int lg = l >> 4, lm = l & 15;
    int ra = i0 + w * 32 + lm;
    const bf16x8* Ap = reinterpret_cast<const bf16x8*>(A);
    const bf16x8* Bp = reinterpret_cast<const bf16x8*>(B);
    bf16x8 a00 = Ap[(size_t)ra * 8 + lg];            // rows [w*32, +16), k 0..31
    bf16x8 a01 = Ap[(size_t)ra * 8 + 4 + lg];        // k 32..63
    bf16x8 a10 = Ap[(size_t)(ra + 16) * 8 + lg];     // rows +16, k 0..31
    bf16x8 a11 = Ap[(size_t)(ra + 16) * 8 + 4 + lg];
#pragma unroll
    for (int ct = 0; ct < 4; ++ct) {
        int rb = j0 + ct * 16 + lm;
        bf16x8 b0 = Bp[(size_t)rb * 8 + lg];
        bf16x8 b1v = Bp[(size_t)rb * 8 + 4 + lg];
        f32x4 acc0 = {0.f, 0.f, 0.f, 0.f};
        f32x4 acc1 = {0.f, 0.f, 0.f, 0.f};
        acc0 = __builtin_amdgcn_mfma_f32_16x16x32_bf16(a00, b0, acc0, 0, 0, 0);
        acc0 = __builtin_amdgcn_mfma_f32_16x16x32_bf16(a01, b1v, acc0, 0, 0, 0);
        acc1 = __builtin_amdgcn_mfma_f32_16x16x32_bf16(a10, b0, acc1, 0, 0, 0);
        acc1 = __builtin_amdgcn_mfma_f32_16x16x32_bf16(a11, b1v, acc1, 0, 0, 0);
        int col = j0 + ct * 16 + lm;
#pragma unroll
        for (int reg = 0; reg < 4; ++reg) {
            int row0 = i0 + w * 32 + lg * 4 + reg;
            float v0 = acc0[reg], v1 = acc1[reg];
            if (SIG) {
                v0 = 1.f / (1.f + __expf(-v0));
                v1 = 1.f / (1.f + __expf(-v1));
            }
            out[(size_t)row0 * ldo + col] = v0;
            out[(size_t)(row0 + 16) * ldo + col] = v1;
        }
    }
}

extern "C" void kernel_launch(void* const* d_in, const int* in_sizes, int n_in,
                              void* d_out, int out_size, void* d_ws, size_t ws_size,
                              hipStream_t stream) {
    const float* x     = (const float*)d_in[0];
    const int*   ei    = (const int*)d_in[1];
    // d_in[2] = adj (unused)
    const float* Wg    = (const float*)d_in[3];
    const float* att_s = (const float*)d_in[4];
    const float* att_d = (const float*)d_in[5];
    const float* bg    = (const float*)d_in[6];
    const float* W1    = (const float*)d_in[7];
    const float* b1    = (const float*)d_in[8];
    const float* W2    = (const float*)d_in[9];
    const float* b2    = (const float*)d_in[10];

    float* ws    = (float*)d_ws;
    float* h     = ws;                            // NN*OD      = 1048576
    float* a_src = h + (size_t)NN * OD;           // NN
    float* a_dst = a_src + NN;                    // NN
    float* denom = a_dst + NN;                    // NN (zeroed, start of zero range)
    float* outg  = denom + NN;                    // NN*OD (zeroed)
    float* xtw   = outg + (size_t)NN * OD;        // FD*EMB (zeroed, end of range)
    float* p     = xtw + FD * EMB;                // NTOT
    __hip_bfloat16* ebf  = (__hip_bfloat16*)(p + NTOT);                    // NN*OD bf16
    __hip_bfloat16* h2bf = (__hip_bfloat16*)((float*)(p + NTOT) + (size_t)NN * OD / 2); // FD*OD bf16

    float* Ahat = (float*)d_out;
    float* Xhat = Ahat + (size_t)NN * NN;

    const int nzero = NN + NN * OD + FD * EMB;    // denom + outg + xtw = 1130496
    k_zero<<<(nzero + 255) / 256, 256, 0, stream>>>(denom, nzero);
    k_gath<<<NN / 16, 256, 0, stream>>>(x, Wg, att_s, att_d, h, a_src, a_dst);
    k_edgep<<<(NTOT + 255) / 256, 256, 0, stream>>>(ei, a_src, a_dst, p, denom);
    k_agg<<<(NTOT + 3) / 4, 256, 0, stream>>>(ei, p, denom, h, outg);
    k_embed<<<NN * OD / 256, 256, 0, stream>>>(outg, bg, ebf);
    k_xtw<<<256, 256, 0, stream>>>(x, W1, xtw);
    k_h2<<<FD / 4, 256, 0, stream>>>(xtw, b1, W2, b2, h2bf);
    k_mm<false><<<dim3(NN / 128, FD / 64), 256, 0, stream>>>(ebf, h2bf, Xhat, FD);
    k_mm<true><<<dim3(NN / 128, NN / 64), 256, 0, stream>>>(ebf, ebf, Ahat, NN);
}

// Round 3
// 698.677 us; speedup vs baseline: 1.0759x; 1.0759x over previous
//
#include <hip/hip_runtime.h>
#include <hip/hip_bf16.h>

#define NN 16384     // nodes
#define FD 512       // feature dim
#define EMB 128      // embed_dim (dense1)
#define OD 64        // out_dim
#define NE 524288    // edges (self-loops handled analytically)

typedef __bf16 bf16x8 __attribute__((ext_vector_type(8)));
typedef float f32x4 __attribute__((ext_vector_type(4)));

// ---------------- zero scratch (deg, cursor, xtw contiguous) ---------------
__global__ void k_zero(int* __restrict__ p, int n) {
    int i = blockIdx.x * 256 + threadIdx.x;
    if (i < n) p[i] = 0;
}

// ---------------- h = x @ W_gat ; a_src = h@att_src ; a_dst = h@att_dst ----
__global__ __launch_bounds__(256) void k_gath(
    const float* __restrict__ x, const float* __restrict__ Wg,
    const float* __restrict__ att_s, const float* __restrict__ att_d,
    float* __restrict__ h, float* __restrict__ a_src, float* __restrict__ a_dst) {
    __shared__ float xs[16 * FD];                      // 32 KB
    int r0 = blockIdx.x * 16;
    const float4* xin = reinterpret_cast<const float4*>(x + (size_t)r0 * FD);
    float4* xls = reinterpret_cast<float4*>(xs);
#pragma unroll
    for (int j = 0; j < 8; ++j) xls[threadIdx.x + 256 * j] = xin[threadIdx.x + 256 * j];
    __syncthreads();
    int c = threadIdx.x & 63;
    int rg = threadIdx.x >> 6;                          // wave id: 4 rows each
    const float* xrow = xs + rg * 4 * FD;
    float acc0 = 0.f, acc1 = 0.f, acc2 = 0.f, acc3 = 0.f;
    for (int k = 0; k < FD; ++k) {
        float w = Wg[k * OD + c];
        acc0 += xrow[k] * w;
        acc1 += xrow[FD + k] * w;
        acc2 += xrow[2 * FD + k] * w;
        acc3 += xrow[3 * FD + k] * w;
    }
    float hv[4] = {acc0, acc1, acc2, acc3};
    float as = att_s[c], ad = att_d[c];
#pragma unroll
    for (int i = 0; i < 4; ++i) {
        int r = r0 + rg * 4 + i;
        h[(size_t)r * OD + c] = hv[i];
        float vs = hv[i] * as, vd = hv[i] * ad;
#pragma unroll
        for (int off = 32; off >= 1; off >>= 1) {
            vs += __shfl_xor(vs, off, 64);
            vd += __shfl_xor(vd, off, 64);
        }
        if (c == 0) { a_src[r] = vs; a_dst[r] = vd; }
    }
}

// ---------------- CSR build: histogram of dst ------------------------------
__global__ void k_hist(const int* __restrict__ ei, int* __restrict__ deg) {
    int i = blockIdx.x * 256 + threadIdx.x;
    if (i < NE) atomicAdd(deg + ei[NE + i], 1);
}

// ---------------- exclusive scan of deg[NN] -> row_start[NN+1] -------------
__global__ __launch_bounds__(256) void k_scan(const int* __restrict__ deg,
                                              int* __restrict__ row_start) {
    __shared__ int part[256];
    int t = threadIdx.x;
    int base = t * (NN / 256);
    int s = 0;
#pragma unroll 8
    for (int j = 0; j < NN / 256; ++j) s += deg[base + j];
    part[t] = s;
    __syncthreads();
    if (t == 0) {
        int run = 0;
        for (int i = 0; i < 256; ++i) { int v = part[i]; part[i] = run; run += v; }
        row_start[NN] = run;
    }
    __syncthreads();
    int run = part[t];
    for (int j = 0; j < NN / 256; ++j) { row_start[base + j] = run; run += deg[base + j]; }
}

// ---------------- scatter src indices into CSR order -----------------------
__global__ void k_scatter(const int* __restrict__ ei, const int* __restrict__ row_start,
                          int* __restrict__ cursor, int* __restrict__ ssrc) {
    int i = blockIdx.x * 256 + threadIdx.x;
    if (i >= NE) return;
    int d = ei[NE + i];
    int pos = atomicAdd(cursor + d, 1);
    ssrc[row_start[d] + pos] = ei[i];
}

// ------- fused softmax+aggregate+bias+leaky+bf16: one wave per dst node ----
// denom = sum exp(leaky(a_src[s]+a_dst[i])), out = sum pv*h[s] / denom
// (softmax max-shift cancels exactly; |e| small so exp is fp32-safe)
__global__ __launch_bounds__(256) void k_aggcsr(
    const int* __restrict__ row_start, const int* __restrict__ ssrc,
    const float* __restrict__ a_src, const float* __restrict__ a_dst,
    const float* __restrict__ h, const float* __restrict__ bg,
    __hip_bfloat16* __restrict__ ebf) {
    int node = blockIdx.x * 4 + (threadIdx.x >> 6);
    int lane = threadIdx.x & 63;
    float ad = a_dst[node];
    // self loop (appended for every node in reference)
    float e0 = a_src[node] + ad;
    e0 = e0 > 0.f ? e0 : 0.5f * e0;
    float p0 = __expf(e0);
    float denom = p0;
    float acc = p0 * h[(size_t)node * OD + lane];
    int j0 = row_start[node], j1 = row_start[node + 1];
    int j = j0;
    // 2-wide software pipeline for load overlap
    for (; j + 2 <= j1; j += 2) {
        int sA = ssrc[j], sB = ssrc[j + 1];
        float hA = h[(size_t)sA * OD + lane];
        float hB = h[(size_t)sB * OD + lane];
        float eA = a_src[sA] + ad, eB = a_src[sB] + ad;
        eA = eA > 0.f ? eA : 0.5f * eA;
        eB = eB > 0.f ? eB : 0.5f * eB;
        float pA = __expf(eA), pB = __expf(eB);
        denom += pA + pB;
        acc += pA * hA + pB * hB;
    }
    if (j < j1) {
        int s = ssrc[j];
        float e = a_src[s] + ad;
        e = e > 0.f ? e : 0.5f * e;
        float pv = __expf(e);
        denom += pv;
        acc += pv * h[(size_t)s * OD + lane];
    }
    float v = acc / denom + bg[lane];
    v = v > 0.f ? v : 0.01f * v;               // embed leaky_relu 0.01
    ebf[(size_t)node * OD + lane] = __float2bfloat16(v);
}

// ---------------- xtw[f][e] = sum_n x[n][f] * W1[n][e]  (partials+atomics) -
__global__ __launch_bounds__(256) void k_xtw(const float* __restrict__ x,
                                             const float* __restrict__ W1,
                                             float* __restrict__ xtw) {
    __shared__ float xs[4][64];
    __shared__ float ws[4][EMB];
    int fb = blockIdx.x & 7;       // 8 f-tiles of 64
    int nc = blockIdx.x >> 3;      // 32 n-chunks of 512
    int f0 = fb * 64;
    int nb = nc * 512;
    int t = threadIdx.x;
    int eb = (t & 15) * 8;         // 8 e per thread
    int fbase = (t >> 4) * 4;      // 4 f per thread
    float acc[4][8] = {};
    for (int n4 = 0; n4 < 512; n4 += 4) {
        { int nn = t >> 6, ff = t & 63;
          xs[nn][ff] = x[(size_t)(nb + n4 + nn) * FD + f0 + ff]; }
#pragma unroll
        for (int j = 0; j < 2; ++j) {
            int idx = t + j * 256;
            ws[idx >> 7][idx & 127] = W1[(size_t)(nb + n4 + (idx >> 7)) * EMB + (idx & 127)];
        }
        __syncthreads();
#pragma unroll
        for (int nn = 0; nn < 4; ++nn) {
            float xv[4], wv[8];
#pragma unroll
            for (int i = 0; i < 4; ++i) xv[i] = xs[nn][fbase + i];
#pragma unroll
            for (int j = 0; j < 8; ++j) wv[j] = ws[nn][eb + j];
#pragma unroll
            for (int i = 0; i < 4; ++i)
#pragma unroll
                for (int j = 0; j < 8; ++j) acc[i][j] += xv[i] * wv[j];
        }
        __syncthreads();
    }
#pragma unroll
    for (int i = 0; i < 4; ++i)
#pragma unroll
        for (int j = 0; j < 8; ++j)
            atomicAdd(xtw + (size_t)(f0 + fbase + i) * EMB + eb + j, acc[i][j]);
}

// ---------------- h2 = relu(xtw + b1) @ W2 + b2 -> bf16 rows ---------------
__global__ __launch_bounds__(256) void k_h2(const float* __restrict__ xtw,
                                            const float* __restrict__ b1,
                                            const float* __restrict__ W2,
                                            const float* __restrict__ b2,
                                            __hip_bfloat16* __restrict__ h2bf) {
    int f = blockIdx.x * 4 + (threadIdx.x >> 6);
    int c = threadIdx.x & 63;
    float acc = b2[c];
    const float* row = xtw + (size_t)f * EMB;
    for (int e = 0; e < EMB; ++e) {
        float hv = row[e] + b1[e];
        hv = hv > 0.f ? hv : 0.f;
        acc += hv * W2[e * OD + c];
    }
    h2bf[(size_t)f * OD + c] = __float2bfloat16(acc);
}

// ---------------- out[i][j] = act( A_rows[i] . B_rows[j] ), K = 64 ---------
template <bool SIG>
__global__ __launch_bounds__(256) void k_mm(const __hip_bfloat16* __restrict__ A,
                                            const __hip_bfloat16* __restrict__ B,
                                            float* __restrict__ out, int ldo) {
    int i0 = blockIdx.x * 128;       // 128 rows per block (4 waves x 32)
    int j0 = blockIdx.y * 64;        // 64 cols per block
    int w = threadIdx.x >> 6;
    int l = threadIdx.x & 63;
    int lg = l >> 4, lm = l & 15;
    int ra = i0 + w * 32 + lm;
    const bf16x8* Ap = reinterpret_cast<const bf16x8*>(A);
    const bf16x8* Bp = reinterpret_cast<const bf16x8*>(B);
    bf16x8 a00 = Ap[(size_t)ra * 8 + lg];            // rows [w*32, +16), k 0..31
    bf16x8 a01 = Ap[(size_t)ra * 8 + 4 + lg];        // k 32..63
    bf16x8 a10 = Ap[(size_t)(ra + 16) * 8 + lg];     // rows +16, k 0..31
    bf16x8 a11 = Ap[(size_t)(ra + 16) * 8 + 4 + lg];
#pragma unroll
    for (int ct = 0; ct < 4; ++ct) {
        int rb = j0 + ct * 16 + lm;
        bf16x8 b0 = Bp[(size_t)rb * 8 + lg];
        bf16x8 b1v = Bp[(size_t)rb * 8 + 4 + lg];
        f32x4 acc0 = {0.f, 0.f, 0.f, 0.f};
        f32x4 acc1 = {0.f, 0.f, 0.f, 0.f};
        acc0 = __builtin_amdgcn_mfma_f32_16x16x32_bf16(a00, b0, acc0, 0, 0, 0);
        acc0 = __builtin_amdgcn_mfma_f32_16x16x32_bf16(a01, b1v, acc0, 0, 0, 0);
        acc1 = __builtin_amdgcn_mfma_f32_16x16x32_bf16(a10, b0, acc1, 0, 0, 0);
        acc1 = __builtin_amdgcn_mfma_f32_16x16x32_bf16(a11, b1v, acc1, 0, 0, 0);
        int col = j0 + ct * 16 + lm;
#pragma unroll
        for (int reg = 0; reg < 4; ++reg) {
            int row0 = i0 + w * 32 + lg * 4 + reg;
            float v0 = acc0[reg], v1 = acc1[reg];
            if (SIG) {
                v0 = 1.f / (1.f + __expf(-v0));
                v1 = 1.f / (1.f + __expf(-v1));
            }
            out[(size_t)row0 * ldo + col] = v0;
            out[(size_t)(row0 + 16) * ldo + col] = v1;
        }
    }
}

extern "C" void kernel_launch(void* const* d_in, const int* in_sizes, int n_in,
                              void* d_out, int out_size, void* d_ws, size_t ws_size,
                              hipStream_t stream) {
    const float* x     = (const float*)d_in[0];
    const int*   ei    = (const int*)d_in[1];
    // d_in[2] = adj (unused)
    const float* Wg    = (const float*)d_in[3];
    const float* att_s = (const float*)d_in[4];
    const float* att_d = (const float*)d_in[5];
    const float* bg    = (const float*)d_in[6];
    const float* W1    = (const float*)d_in[7];
    const float* b1    = (const float*)d_in[8];
    const float* W2    = (const float*)d_in[9];
    const float* b2    = (const float*)d_in[10];

    float* ws    = (float*)d_ws;
    float* h     = ws;                             // NN*OD f32
    float* a_src = h + (size_t)NN * OD;            // NN
    float* a_dst = a_src + NN;                     // NN
    int*   row_start = (int*)(a_dst + NN);         // NN+1
    int*   ssrc  = row_start + NN + 1;             // NE
    int*   deg   = ssrc + NE;                      // NN   (zeroed, start)
    int*   cursor= deg + NN;                       // NN   (zeroed)
    float* xtw   = (float*)(cursor + NN);          // FD*EMB (zeroed, end)
    __hip_bfloat16* ebf  = (__hip_bfloat16*)(xtw + FD * EMB);      // NN*OD bf16
    __hip_bfloat16* h2bf = ebf + (size_t)NN * OD;                  // FD*OD bf16

    float* Ahat = (float*)d_out;
    float* Xhat = Ahat + (size_t)NN * NN;

    const int nzero = NN + NN + FD * EMB;          // deg + cursor + xtw
    k_zero<<<(nzero + 255) / 256, 256, 0, stream>>>(deg, nzero);
    k_gath<<<NN / 16, 256, 0, stream>>>(x, Wg, att_s, att_d, h, a_src, a_dst);
    k_hist<<<(NE + 255) / 256, 256, 0, stream>>>(ei, deg);
    k_scan<<<1, 256, 0, stream>>>(deg, row_start);
    k_scatter<<<(NE + 255) / 256, 256, 0, stream>>>(ei, row_start, cursor, ssrc);
    k_aggcsr<<<NN / 4, 256, 0, stream>>>(row_start, ssrc, a_src, a_dst, h, bg, ebf);
    k_xtw<<<256, 256, 0, stream>>>(x, W1, xtw);
    k_h2<<<FD / 4, 256, 0, stream>>>(xtw, b1, W2, b2, h2bf);
    k_mm<false><<<dim3(NN / 128, FD / 64), 256, 0, stream>>>(ebf, h2bf, Xhat, FD);
    k_mm<true><<<dim3(NN / 128, NN / 64), 256, 0, stream>>>(ebf, ebf, Ahat, NN);
}

// Round 4
// 682.160 us; speedup vs baseline: 1.1020x; 1.0242x over previous
//
#include <hip/hip_runtime.h>
#include <hip/hip_bf16.h>

#define NN 16384     // nodes
#define FD 512       // feature dim
#define EMB 128      // embed_dim (dense1)
#define OD 64        // out_dim
#define NE 524288    // edges (self-loops handled analytically)

typedef __bf16 bf16x8 __attribute__((ext_vector_type(8)));
typedef float f32x4 __attribute__((ext_vector_type(4)));
typedef unsigned short u16;

__device__ inline float bfu2f(u16 u) {
    unsigned int x = (unsigned int)u << 16;
    float f;
    __builtin_memcpy(&f, &x, 4);
    return f;
}

// ---------------- zero scratch (xtw, deg, cursor contiguous) ---------------
__global__ void k_zero(int* __restrict__ p, int n) {
    int i = blockIdx.x * 256 + threadIdx.x;
    if (i < n) p[i] = 0;
}

// ---------------- x (f32) -> xbf (bf16), 8 elems/thread --------------------
__global__ void k_cvt(const float* __restrict__ x, __hip_bfloat16* __restrict__ xbf) {
    size_t i = ((size_t)blockIdx.x * 256 + threadIdx.x) * 8;
    float4 v0 = *reinterpret_cast<const float4*>(x + i);
    float4 v1 = *reinterpret_cast<const float4*>(x + i + 4);
    __hip_bfloat16 o[8];
    o[0] = __float2bfloat16(v0.x); o[1] = __float2bfloat16(v0.y);
    o[2] = __float2bfloat16(v0.z); o[3] = __float2bfloat16(v0.w);
    o[4] = __float2bfloat16(v1.x); o[5] = __float2bfloat16(v1.y);
    o[6] = __float2bfloat16(v1.z); o[7] = __float2bfloat16(v1.w);
    *reinterpret_cast<uint4*>(xbf + i) = *reinterpret_cast<const uint4*>(o);
}

// ---------------- WgT[c][k] = bf16(Wg[k][c])  (64 x 512) -------------------
__global__ void k_wgt(const float* __restrict__ Wg, __hip_bfloat16* __restrict__ WgT) {
    int t = threadIdx.x;
    int c = t >> 2;
    int k0 = (t & 3) * 128;
    for (int j = 0; j < 128; ++j)
        WgT[c * 512 + k0 + j] = __float2bfloat16(Wg[(size_t)(k0 + j) * OD + c]);
}

// -------- h = xbf @ Wg (MFMA, f32 acc) -> hbf; a_src/a_dst via reduce ------
__global__ __launch_bounds__(256) void k_hmm(
    const __hip_bfloat16* __restrict__ xbf, const __hip_bfloat16* __restrict__ WgT,
    const float* __restrict__ att_s, const float* __restrict__ att_d,
    __hip_bfloat16* __restrict__ hbf, float* __restrict__ a_src, float* __restrict__ a_dst) {
    int w = threadIdx.x >> 6, l = threadIdx.x & 63;
    int lg = l >> 4, lm = l & 15;
    int r0 = blockIdx.x * 64 + w * 16;
    const bf16x8* Xp = reinterpret_cast<const bf16x8*>(xbf);
    const bf16x8* Wp = reinterpret_cast<const bf16x8*>(WgT);
    bf16x8 a[16];
    size_t abase = (size_t)(r0 + lm) * 64 + lg;          // row stride 512 elems = 64 chunks
#pragma unroll
    for (int kc = 0; kc < 16; ++kc) a[kc] = Xp[abase + kc * 4];
    f32x4 acc[4];
#pragma unroll
    for (int j = 0; j < 4; ++j) {
        f32x4 c = {0.f, 0.f, 0.f, 0.f};
        size_t bbase = (size_t)(j * 16 + lm) * 64 + lg;
#pragma unroll
        for (int kc = 0; kc < 16; ++kc)
            c = __builtin_amdgcn_mfma_f32_16x16x32_bf16(a[kc], Wp[bbase + kc * 4], c, 0, 0, 0);
        acc[j] = c;
    }
#pragma unroll
    for (int j = 0; j < 4; ++j)
#pragma unroll
        for (int reg = 0; reg < 4; ++reg)
            hbf[(size_t)(r0 + lg * 4 + reg) * OD + j * 16 + lm] = __float2bfloat16(acc[j][reg]);
    float ats0 = att_s[lm], ats1 = att_s[16 + lm], ats2 = att_s[32 + lm], ats3 = att_s[48 + lm];
    float atd0 = att_d[lm], atd1 = att_d[16 + lm], atd2 = att_d[32 + lm], atd3 = att_d[48 + lm];
#pragma unroll
    for (int reg = 0; reg < 4; ++reg) {
        float ps = acc[0][reg] * ats0 + acc[1][reg] * ats1 + acc[2][reg] * ats2 + acc[3][reg] * ats3;
        float pd = acc[0][reg] * atd0 + acc[1][reg] * atd1 + acc[2][reg] * atd2 + acc[3][reg] * atd3;
#pragma unroll
        for (int off = 1; off < 16; off <<= 1) {
            ps += __shfl_xor(ps, off, 64);
            pd += __shfl_xor(pd, off, 64);
        }
        if (lm == 0) {
            int r = r0 + lg * 4 + reg;
            a_src[r] = ps;
            a_dst[r] = pd;
        }
    }
}

// ---------------- CSR build: histogram of dst ------------------------------
__global__ void k_hist(const int* __restrict__ ei, int* __restrict__ deg) {
    int i = blockIdx.x * 256 + threadIdx.x;
    if (i < NE) atomicAdd(deg + ei[NE + i], 1);
}

// ---------------- exclusive scan deg[NN] -> row_start (parallel) -----------
__global__ __launch_bounds__(256) void k_scan(const int* __restrict__ deg,
                                              int* __restrict__ row_start) {
    __shared__ int part[256];
    int t = threadIdx.x;
    int base = t * 64;                                   // NN/256 = 64
    int s = 0;
    for (int j = 0; j < 64; ++j) s += deg[base + j];
    part[t] = s;
    __syncthreads();
    for (int off = 1; off < 256; off <<= 1) {
        int v = (t >= off) ? part[t - off] : 0;
        __syncthreads();
        part[t] += v;
        __syncthreads();
    }
    int run = part[t] - s;                               // exclusive
    if (t == 255) row_start[NN] = part[255];
    for (int j = 0; j < 64; ++j) { row_start[base + j] = run; run += deg[base + j]; }
}

// ---------------- scatter src indices into CSR order -----------------------
__global__ void k_scatter(const int* __restrict__ ei, const int* __restrict__ row_start,
                          int* __restrict__ cursor, int* __restrict__ ssrc) {
    int i = blockIdx.x * 256 + threadIdx.x;
    if (i >= NE) return;
    int d = ei[NE + i];
    int pos = atomicAdd(cursor + d, 1);
    ssrc[row_start[d] + pos] = ei[i];
}

// ------- fused softmax+aggregate+bias+leaky+bf16: one wave per dst node ----
__global__ __launch_bounds__(256) void k_aggcsr(
    const int* __restrict__ row_start, const int* __restrict__ ssrc,
    const float* __restrict__ a_src, const float* __restrict__ a_dst,
    const u16* __restrict__ hb, const float* __restrict__ bg,
    __hip_bfloat16* __restrict__ ebf) {
    int node = blockIdx.x * 4 + (threadIdx.x >> 6);
    int lane = threadIdx.x & 63;
    float ad = a_dst[node];
    float e0 = a_src[node] + ad;                 // self loop
    e0 = e0 > 0.f ? e0 : 0.5f * e0;
    float p0 = __expf(e0);
    float denom = p0;
    float acc = p0 * bfu2f(hb[(size_t)node * OD + lane]);
    int j0 = row_start[node], j1 = row_start[node + 1];
    int j = j0;
    for (; j + 2 <= j1; j += 2) {
        int sA = ssrc[j], sB = ssrc[j + 1];
        float hA = bfu2f(hb[(size_t)sA * OD + lane]);
        float hB = bfu2f(hb[(size_t)sB * OD + lane]);
        float eA = a_src[sA] + ad, eB = a_src[sB] + ad;
        eA = eA > 0.f ? eA : 0.5f * eA;
        eB = eB > 0.f ? eB : 0.5f * eB;
        float pA = __expf(eA), pB = __expf(eB);
        denom += pA + pB;
        acc += pA * hA + pB * hB;
    }
    if (j < j1) {
        int s = ssrc[j];
        float e = a_src[s] + ad;
        e = e > 0.f ? e : 0.5f * e;
        float pv = __expf(e);
        denom += pv;
        acc += pv * bfu2f(hb[(size_t)s * OD + lane]);
    }
    float v = acc * __builtin_amdgcn_rcpf(denom) + bg[lane];
    v = v > 0.f ? v : 0.01f * v;                 // embed leaky_relu 0.01
    ebf[(size_t)node * OD + lane] = __float2bfloat16(v);
}

// ---------------- xtw[f][e] = sum_n x[n][f] * W1[n][e]  (partials+atomics) -
__global__ __launch_bounds__(256) void k_xtw(const float* __restrict__ x,
                                             const float* __restrict__ W1,
                                             float* __restrict__ xtw) {
    __shared__ float xs[4][64];
    __shared__ float ws[4][EMB];
    int fb = blockIdx.x & 7;       // 8 f-tiles of 64
    int nc = blockIdx.x >> 3;      // 32 n-chunks of 512
    int f0 = fb * 64;
    int nb = nc * 512;
    int t = threadIdx.x;
    int eb = (t & 15) * 8;         // 8 e per thread
    int fbase = (t >> 4) * 4;      // 4 f per thread
    float acc[4][8] = {};
    for (int n4 = 0; n4 < 512; n4 += 4) {
        { int nn = t >> 6, ff = t & 63;
          xs[nn][ff] = x[(size_t)(nb + n4 + nn) * FD + f0 + ff]; }
#pragma unroll
        for (int j = 0; j < 2; ++j) {
            int idx = t + j * 256;
            ws[idx >> 7][idx & 127] = W1[(size_t)(nb + n4 + (idx >> 7)) * EMB + (idx & 127)];
        }
        __syncthreads();
#pragma unroll
        for (int nn = 0; nn < 4; ++nn) {
            float xv[4], wv[8];
#pragma unroll
            for (int i = 0; i < 4; ++i) xv[i] = xs[nn][fbase + i];
#pragma unroll
            for (int j = 0; j < 8; ++j) wv[j] = ws[nn][eb + j];
#pragma unroll
            for (int i = 0; i < 4; ++i)
#pragma unroll
                for (int j = 0; j < 8; ++j) acc[i][j] += xv[i] * wv[j];
        }
        __syncthreads();
    }
#pragma unroll
    for (int i = 0; i < 4; ++i)
#pragma unroll
        for (int j = 0; j < 8; ++j)
            atomicAdd(xtw + (size_t)(f0 + fbase + i) * EMB + eb + j, acc[i][j]);
}

// ---------------- h2 = relu(xtw + b1) @ W2 + b2 -> bf16 rows ---------------
__global__ __launch_bounds__(256) void k_h2(const float* __restrict__ xtw,
                                            const float* __restrict__ b1,
                                            const float* __restrict__ W2,
                                            const float* __restrict__ b2,
                                            __hip_bfloat16* __restrict__ h2bf) {
    int f = blockIdx.x * 4 + (threadIdx.x >> 6);
    int c = threadIdx.x & 63;
    float acc = b2[c];
    const float* row = xtw + (size_t)f * EMB;
    for (int e = 0; e < EMB; ++e) {
        float hv = row[e] + b1[e];
        hv = hv > 0.f ? hv : 0.f;
        acc += hv * W2[e * OD + c];
    }
    h2bf[(size_t)f * OD + c] = __float2bfloat16(acc);
}

// ---------------- out[i][j] = act( A_rows[i] . B_rows[j] ), K = 64 ---------
template <bool SIG>
__global__ __launch_bounds__(256) void k_mm(const __hip_bfloat16* __restrict__ A,
                                            const __hip_bfloat16* __restrict__ B,
                                            float* __restrict__ out, int ldo) {
    int i0 = blockIdx.x * 128;       // 128 rows per block (4 waves x 32)
    int j0 = blockIdx.y * 64;        // 64 cols per block
    int w = threadIdx.x >> 6;
    int l = threadIdx.x & 63;
    int lg = l >> 4, lm = l & 15;
    int ra = i0 + w * 32 + lm;
    const bf16x8* Ap = reinterpret_cast<const bf16x8*>(A);
    const bf16x8* Bp = reinterpret_cast<const bf16x8*>(B);
    bf16x8 a00 = Ap[(size_t)ra * 8 + lg];            // rows [w*32, +16), k 0..31
    bf16x8 a01 = Ap[(size_t)ra * 8 + 4 + lg];        // k 32..63
    bf16x8 a10 = Ap[(size_t)(ra + 16) * 8 + lg];     // rows +16, k 0..31
    bf16x8 a11 = Ap[(size_t)(ra + 16) * 8 + 4 + lg];
#pragma unroll
    for (int ct = 0; ct < 4; ++ct) {
        int rb = j0 + ct * 16 + lm;
        bf16x8 b0 = Bp[(size_t)rb * 8 + lg];
        bf16x8 b1v = Bp[(size_t)rb * 8 + 4 + lg];
        f32x4 acc0 = {0.f, 0.f, 0.f, 0.f};
        f32x4 acc1 = {0.f, 0.f, 0.f, 0.f};
        acc0 = __builtin_amdgcn_mfma_f32_16x16x32_bf16(a00, b0, acc0, 0, 0, 0);
        acc0 = __builtin_amdgcn_mfma_f32_16x16x32_bf16(a01, b1v, acc0, 0, 0, 0);
        acc1 = __builtin_amdgcn_mfma_f32_16x16x32_bf16(a10, b0, acc1, 0, 0, 0);
        acc1 = __builtin_amdgcn_mfma_f32_16x16x32_bf16(a11, b1v, acc1, 0, 0, 0);
        int col = j0 + ct * 16 + lm;
#pragma unroll
        for (int reg = 0; reg < 4; ++reg) {
            int row0 = i0 + w * 32 + lg * 4 + reg;
            float v0 = acc0[reg], v1 = acc1[reg];
            if (SIG) {
                v0 = __builtin_amdgcn_rcpf(1.f + __expf(-v0));
                v1 = __builtin_amdgcn_rcpf(1.f + __expf(-v1));
            }
            __builtin_nontemporal_store(v0, &out[(size_t)row0 * ldo + col]);
            __builtin_nontemporal_store(v1, &out[(size_t)(row0 + 16) * ldo + col]);
        }
    }
}

extern "C" void kernel_launch(void* const* d_in, const int* in_sizes, int n_in,
                              void* d_out, int out_size, void* d_ws, size_t ws_size,
                              hipStream_t stream) {
    const float* x     = (const float*)d_in[0];
    const int*   ei    = (const int*)d_in[1];
    // d_in[2] = adj (unused)
    const float* Wg    = (const float*)d_in[3];
    const float* att_s = (const float*)d_in[4];
    const float* att_d = (const float*)d_in[5];
    const float* bg    = (const float*)d_in[6];
    const float* W1    = (const float*)d_in[7];
    const float* b1    = (const float*)d_in[8];
    const float* W2    = (const float*)d_in[9];
    const float* b2    = (const float*)d_in[10];

    float* ws    = (float*)d_ws;
    float* a_src = ws;                              // NN
    float* a_dst = a_src + NN;                      // NN
    float* xtw   = a_dst + NN;                      // FD*EMB f32 [zero start]
    int*   deg   = (int*)(xtw + FD * EMB);          // NN [zeroed]
    int*   cursor= deg + NN;                        // NN [zeroed, end of range]
    int*   row_start = cursor + NN;                 // NN+4 (padded for 16B alignment)
    int*   ssrc  = row_start + NN + 4;              // NE
    __hip_bfloat16* xbf  = (__hip_bfloat16*)(ssrc + NE);       // NN*FD
    __hip_bfloat16* WgT  = xbf + (size_t)NN * FD;              // OD*FD
    __hip_bfloat16* hbf  = WgT + (size_t)OD * FD;              // NN*OD
    __hip_bfloat16* ebf  = hbf + (size_t)NN * OD;              // NN*OD
    __hip_bfloat16* h2bf = ebf + (size_t)NN * OD;              // FD*OD

    float* Ahat = (float*)d_out;
    float* Xhat = Ahat + (size_t)NN * NN;

    const int nzero = FD * EMB + NN + NN;           // xtw + deg + cursor
    k_zero<<<(nzero + 255) / 256, 256, 0, stream>>>((int*)xtw, nzero);
    k_cvt<<<NN * FD / 2048, 256, 0, stream>>>(x, xbf);
    k_wgt<<<1, 256, 0, stream>>>(Wg, WgT);
    k_hist<<<(NE + 255) / 256, 256, 0, stream>>>(ei, deg);
    k_scan<<<1, 256, 0, stream>>>(deg, row_start);
    k_scatter<<<(NE + 255) / 256, 256, 0, stream>>>(ei, row_start, cursor, ssrc);
    k_hmm<<<NN / 64, 256, 0, stream>>>(xbf, WgT, att_s, att_d, hbf, a_src, a_dst);
    k_aggcsr<<<NN / 4, 256, 0, stream>>>(row_start, ssrc, a_src, a_dst,
                                         (const u16*)hbf, bg, ebf);
    k_xtw<<<256, 256, 0, stream>>>(x, W1, xtw);
    k_h2<<<FD / 4, 256, 0, stream>>>(xtw, b1, W2, b2, h2bf);
    k_mm<false><<<dim3(NN / 128, FD / 64), 256, 0, stream>>>(ebf, h2bf, Xhat, FD);
    k_mm<true><<<dim3(NN / 128, NN / 64), 256, 0, stream>>>(ebf, ebf, Ahat, NN);
}

// Round 6
// 516.366 us; speedup vs baseline: 1.4558x; 1.3211x over previous
//
#include <hip/hip_runtime.h>
#include <hip/hip_bf16.h>

#define NN 16384     // nodes
#define FD 512       // feature dim
#define EMB 128      // embed_dim (dense1)
#define OD 64        // out_dim
#define NE 524288    // edges (self-loops handled analytically)

typedef __bf16 bf16x8 __attribute__((ext_vector_type(8)));
typedef float f32x4 __attribute__((ext_vector_type(4)));
typedef unsigned short u16;

__device__ inline float bfu2f(u16 u) {
    unsigned int x = (unsigned int)u << 16;
    float f;
    __builtin_memcpy(&f, &x, 4);
    return f;
}

// ===== fused prep: zero scratch | x->bf16 | WgT | dst histogram =============
__global__ __launch_bounds__(256) void k_prep(
    const float* __restrict__ x, __hip_bfloat16* __restrict__ xbf,
    const float* __restrict__ Wg, __hip_bfloat16* __restrict__ WgT,
    const int* __restrict__ ei, int* __restrict__ deg, int* __restrict__ zbase) {
    int b = blockIdx.x;
    if (b < 384) {                                   // zero xtw+deg+cursor
        int i = b * 256 + threadIdx.x;
        if (i < FD * EMB + 2 * NN) zbase[i] = 0;
        return;
    }
    b -= 384;
    if (b < NN * FD / 2048) {                        // x -> bf16
        size_t i = ((size_t)b * 256 + threadIdx.x) * 8;
        float4 v0 = *reinterpret_cast<const float4*>(x + i);
        float4 v1 = *reinterpret_cast<const float4*>(x + i + 4);
        __hip_bfloat16 o[8];
        o[0] = __float2bfloat16(v0.x); o[1] = __float2bfloat16(v0.y);
        o[2] = __float2bfloat16(v0.z); o[3] = __float2bfloat16(v0.w);
        o[4] = __float2bfloat16(v1.x); o[5] = __float2bfloat16(v1.y);
        o[6] = __float2bfloat16(v1.z); o[7] = __float2bfloat16(v1.w);
        *reinterpret_cast<uint4*>(xbf + i) = *reinterpret_cast<const uint4*>(o);
        return;
    }
    b -= NN * FD / 2048;
    if (b < 1) {                                     // WgT[c][k] = Wg[k][c]
        int t = threadIdx.x;
        int c = t >> 2;
        int k0 = (t & 3) * 128;
        for (int j = 0; j < 128; ++j)
            WgT[c * 512 + k0 + j] = __float2bfloat16(Wg[(size_t)(k0 + j) * OD + c]);
        return;
    }
    b -= 1;
    {                                                // histogram of dst
        int i = b * 256 + threadIdx.x;
        if (i < NE) atomicAdd(deg + ei[NE + i], 1);
    }
}

// ---------------- exclusive scan deg[NN] -> row_start (parallel) -----------
__global__ __launch_bounds__(256) void k_scan(const int* __restrict__ deg,
                                              int* __restrict__ row_start) {
    __shared__ int part[256];
    int t = threadIdx.x;
    int base = t * 64;                                   // NN/256 = 64
    int s = 0;
    for (int j = 0; j < 64; ++j) s += deg[base + j];
    part[t] = s;
    __syncthreads();
    for (int off = 1; off < 256; off <<= 1) {
        int v = (t >= off) ? part[t - off] : 0;
        __syncthreads();
        part[t] += v;
        __syncthreads();
    }
    int run = part[t] - s;                               // exclusive
    if (t == 255) row_start[NN] = part[255];
    for (int j = 0; j < 64; ++j) { row_start[base + j] = run; run += deg[base + j]; }
}

// ===== fused: CSR scatter | h = xbf@Wg MFMA + a_src/a_dst ===================
__global__ __launch_bounds__(256) void k_scat_hmm(
    const int* __restrict__ ei, const int* __restrict__ row_start,
    int* __restrict__ cursor, int* __restrict__ ssrc,
    const __hip_bfloat16* __restrict__ xbf, const __hip_bfloat16* __restrict__ WgT,
    const float* __restrict__ att_s, const float* __restrict__ att_d,
    __hip_bfloat16* __restrict__ hbf, float* __restrict__ a_src, float* __restrict__ a_dst) {
    int b = blockIdx.x;
    if (b < NE / 256) {                              // scatter
        int i = b * 256 + threadIdx.x;
        int d = ei[NE + i];
        int pos = atomicAdd(cursor + d, 1);
        ssrc[row_start[d] + pos] = ei[i];
        return;
    }
    b -= NE / 256;
    // hmm: h = xbf @ WgT^T (MFMA), 64 rows per block
    int w = threadIdx.x >> 6, l = threadIdx.x & 63;
    int lg = l >> 4, lm = l & 15;
    int r0 = b * 64 + w * 16;
    const bf16x8* Xp = reinterpret_cast<const bf16x8*>(xbf);
    const bf16x8* Wp = reinterpret_cast<const bf16x8*>(WgT);
    bf16x8 a[16];
    size_t abase = (size_t)(r0 + lm) * 64 + lg;          // row stride 512 = 64 chunks
#pragma unroll
    for (int kc = 0; kc < 16; ++kc) a[kc] = Xp[abase + kc * 4];
    f32x4 acc[4];
#pragma unroll
    for (int j = 0; j < 4; ++j) {
        f32x4 c = {0.f, 0.f, 0.f, 0.f};
        size_t bbase = (size_t)(j * 16 + lm) * 64 + lg;
#pragma unroll
        for (int kc = 0; kc < 16; ++kc)
            c = __builtin_amdgcn_mfma_f32_16x16x32_bf16(a[kc], Wp[bbase + kc * 4], c, 0, 0, 0);
        acc[j] = c;
    }
#pragma unroll
    for (int j = 0; j < 4; ++j)
#pragma unroll
        for (int reg = 0; reg < 4; ++reg)
            hbf[(size_t)(r0 + lg * 4 + reg) * OD + j * 16 + lm] = __float2bfloat16(acc[j][reg]);
    float ats0 = att_s[lm], ats1 = att_s[16 + lm], ats2 = att_s[32 + lm], ats3 = att_s[48 + lm];
    float atd0 = att_d[lm], atd1 = att_d[16 + lm], atd2 = att_d[32 + lm], atd3 = att_d[48 + lm];
#pragma unroll
    for (int reg = 0; reg < 4; ++reg) {
        float ps = acc[0][reg] * ats0 + acc[1][reg] * ats1 + acc[2][reg] * ats2 + acc[3][reg] * ats3;
        float pd = acc[0][reg] * atd0 + acc[1][reg] * atd1 + acc[2][reg] * atd2 + acc[3][reg] * atd3;
#pragma unroll
        for (int off = 1; off < 16; off <<= 1) {
            ps += __shfl_xor(ps, off, 64);
            pd += __shfl_xor(pd, off, 64);
        }
        if (lm == 0) {
            int r = r0 + lg * 4 + reg;
            a_src[r] = ps;
            a_dst[r] = pd;
        }
    }
}

// ------- fused softmax+aggregate+bias+leaky+bf16: one wave per dst node ----
__global__ __launch_bounds__(256) void k_aggcsr(
    const int* __restrict__ row_start, const int* __restrict__ ssrc,
    const float* __restrict__ a_src, const float* __restrict__ a_dst,
    const u16* __restrict__ hb, const float* __restrict__ bg,
    __hip_bfloat16* __restrict__ ebf) {
    int node = blockIdx.x * 4 + (threadIdx.x >> 6);
    int lane = threadIdx.x & 63;
    float ad = a_dst[node];
    float e0 = a_src[node] + ad;                 // self loop
    e0 = e0 > 0.f ? e0 : 0.5f * e0;
    float p0 = __expf(e0);
    float denom = p0;
    float acc = p0 * bfu2f(hb[(size_t)node * OD + lane]);
    int j0 = row_start[node], j1 = row_start[node + 1];
    int j = j0;
    for (; j + 2 <= j1; j += 2) {
        int sA = ssrc[j], sB = ssrc[j + 1];
        float hA = bfu2f(hb[(size_t)sA * OD + lane]);
        float hB = bfu2f(hb[(size_t)sB * OD + lane]);
        float eA = a_src[sA] + ad, eB = a_src[sB] + ad;
        eA = eA > 0.f ? eA : 0.5f * eA;
        eB = eB > 0.f ? eB : 0.5f * eB;
        float pA = __expf(eA), pB = __expf(eB);
        denom += pA + pB;
        acc += pA * hA + pB * hB;
    }
    if (j < j1) {
        int s = ssrc[j];
        float e = a_src[s] + ad;
        e = e > 0.f ? e : 0.5f * e;
        float pv = __expf(e);
        denom += pv;
        acc += pv * bfu2f(hb[(size_t)s * OD + lane]);
    }
    float v = acc * __builtin_amdgcn_rcpf(denom) + bg[lane];
    v = v > 0.f ? v : 0.01f * v;                 // embed leaky_relu 0.01
    ebf[(size_t)node * OD + lane] = __float2bfloat16(v);
}

// ---------------- xtw[f][e] = sum_n x[n][f] * W1[n][e]  (partials+atomics) -
__global__ __launch_bounds__(256) void k_xtw(const float* __restrict__ x,
                                             const float* __restrict__ W1,
                                             float* __restrict__ xtw) {
    __shared__ float xs[4][64];
    __shared__ float ws[4][EMB];
    int fb = blockIdx.x & 7;       // 8 f-tiles of 64
    int nc = blockIdx.x >> 3;      // 32 n-chunks of 512
    int f0 = fb * 64;
    int nb = nc * 512;
    int t = threadIdx.x;
    int eb = (t & 15) * 8;         // 8 e per thread
    int fbase = (t >> 4) * 4;      // 4 f per thread
    float acc[4][8] = {};
    for (int n4 = 0; n4 < 512; n4 += 4) {
        { int nn = t >> 6, ff = t & 63;
          xs[nn][ff] = x[(size_t)(nb + n4 + nn) * FD + f0 + ff]; }
#pragma unroll
        for (int j = 0; j < 2; ++j) {
            int idx = t + j * 256;
            ws[idx >> 7][idx & 127] = W1[(size_t)(nb + n4 + (idx >> 7)) * EMB + (idx & 127)];
        }
        __syncthreads();
#pragma unroll
        for (int nn = 0; nn < 4; ++nn) {
            float xv[4], wv[8];
#pragma unroll
            for (int i = 0; i < 4; ++i) xv[i] = xs[nn][fbase + i];
#pragma unroll
            for (int j = 0; j < 8; ++j) wv[j] = ws[nn][eb + j];
#pragma unroll
            for (int i = 0; i < 4; ++i)
#pragma unroll
                for (int j = 0; j < 8; ++j) acc[i][j] += xv[i] * wv[j];
        }
        __syncthreads();
    }
#pragma unroll
    for (int i = 0; i < 4; ++i)
#pragma unroll
        for (int j = 0; j < 8; ++j)
            atomicAdd(xtw + (size_t)(f0 + fbase + i) * EMB + eb + j, acc[i][j]);
}

// ---------------- h2 = relu(xtw + b1) @ W2 + b2 -> bf16 rows ---------------
__global__ __launch_bounds__(256) void k_h2(const float* __restrict__ xtw,
                                            const float* __restrict__ b1,
                                            const float* __restrict__ W2,
                                            const float* __restrict__ b2,
                                            __hip_bfloat16* __restrict__ h2bf) {
    int f = blockIdx.x * 4 + (threadIdx.x >> 6);
    int c = threadIdx.x & 63;
    float acc = b2[c];
    const float* row = xtw + (size_t)f * EMB;
    for (int e = 0; e < EMB; ++e) {
        float hv = row[e] + b1[e];
        hv = hv > 0.f ? hv : 0.f;
        acc += hv * W2[e * OD + c];
    }
    h2bf[(size_t)f * OD + c] = __float2bfloat16(acc);
}

// ---------------- X_hat = ebf @ h2bf^T (small, 33 MB out) ------------------
__global__ __launch_bounds__(256) void k_mmX(const __hip_bfloat16* __restrict__ A,
                                             const __hip_bfloat16* __restrict__ B,
                                             float* __restrict__ out, int ldo) {
    int i0 = blockIdx.x * 128;
    int j0 = blockIdx.y * 64;
    int w = threadIdx.x >> 6;
    int l = threadIdx.x & 63;
    int lg = l >> 4, lm = l & 15;
    int ra = i0 + w * 32 + lm;
    const bf16x8* Ap = reinterpret_cast<const bf16x8*>(A);
    const bf16x8* Bp = reinterpret_cast<const bf16x8*>(B);
    bf16x8 a00 = Ap[(size_t)ra * 8 + lg];
    bf16x8 a01 = Ap[(size_t)ra * 8 + 4 + lg];
    bf16x8 a10 = Ap[(size_t)(ra + 16) * 8 + lg];
    bf16x8 a11 = Ap[(size_t)(ra + 16) * 8 + 4 + lg];
#pragma unroll
    for (int ct = 0; ct < 4; ++ct) {
        int rb = j0 + ct * 16 + lm;
        bf16x8 b0 = Bp[(size_t)rb * 8 + lg];
        bf16x8 b1v = Bp[(size_t)rb * 8 + 4 + lg];
        f32x4 acc0 = {0.f, 0.f, 0.f, 0.f};
        f32x4 acc1 = {0.f, 0.f, 0.f, 0.f};
        acc0 = __builtin_amdgcn_mfma_f32_16x16x32_bf16(a00, b0, acc0, 0, 0, 0);
        acc0 = __builtin_amdgcn_mfma_f32_16x16x32_bf16(a01, b1v, acc0, 0, 0, 0);
        acc1 = __builtin_amdgcn_mfma_f32_16x16x32_bf16(a10, b0, acc1, 0, 0, 0);
        acc1 = __builtin_amdgcn_mfma_f32_16x16x32_bf16(a11, b1v, acc1, 0, 0, 0);
        int col = j0 + ct * 16 + lm;
#pragma unroll
        for (int reg = 0; reg < 4; ++reg) {
            int row0 = i0 + w * 32 + lg * 4 + reg;
            __builtin_nontemporal_store(acc0[reg], &out[(size_t)row0 * ldo + col]);
            __builtin_nontemporal_store(acc1[reg], &out[(size_t)(row0 + 16) * ldo + col]);
        }
    }
}

// ===== A_hat = sigmoid(ebf @ ebf^T): 128x128 block, LDS transpose epilogue =
// Per wave: 32 rows x 128 cols. Epilogue stages sigmoid(acc) in per-wave LDS,
// reads back f32x4/lane -> global_store_dwordx4 (4x256B contiguous chunks).
__global__ __launch_bounds__(256) void k_mmA(const __hip_bfloat16* __restrict__ A,
                                             float* __restrict__ out) {
    __shared__ float ls[4][32 * 68];                 // 34.8 KB, per-wave private
    int w = threadIdx.x >> 6, l = threadIdx.x & 63;
    int lg = l >> 4, lm = l & 15;
    int i0 = blockIdx.x * 128 + w * 32;
    int j0 = blockIdx.y * 128;
    const bf16x8* Ap = reinterpret_cast<const bf16x8*>(A);
    size_t arow = (size_t)(i0 + lm) * 8;             // row stride 64 bf16 = 8 chunks
    bf16x8 a0 = Ap[arow + lg];                       // rows lo, k 0..31
    bf16x8 a1 = Ap[arow + 4 + lg];                   // rows lo, k 32..63
    bf16x8 a2 = Ap[arow + 128 + lg];                 // rows +16, k 0..31
    bf16x8 a3 = Ap[arow + 128 + 4 + lg];
    f32x4 accL[8], accH[8];
#pragma unroll
    for (int ct = 0; ct < 8; ++ct) {
        size_t brow = (size_t)(j0 + ct * 16 + lm) * 8;
        bf16x8 b0 = Ap[brow + lg];
        bf16x8 b1 = Ap[brow + 4 + lg];
        f32x4 cL = {0.f, 0.f, 0.f, 0.f};
        f32x4 cH = {0.f, 0.f, 0.f, 0.f};
        cL = __builtin_amdgcn_mfma_f32_16x16x32_bf16(a0, b0, cL, 0, 0, 0);
        cL = __builtin_amdgcn_mfma_f32_16x16x32_bf16(a1, b1, cL, 0, 0, 0);
        cH = __builtin_amdgcn_mfma_f32_16x16x32_bf16(a2, b0, cH, 0, 0, 0);
        cH = __builtin_amdgcn_mfma_f32_16x16x32_bf16(a3, b1, cH, 0, 0, 0);
        accL[ct] = cL;
        accH[ct] = cH;
    }
    float* myl = ls[w];
#pragma unroll
    for (int ph = 0; ph < 2; ++ph) {
        // stage 32x64 sigmoid tile
#pragma unroll
        for (int c4 = 0; c4 < 4; ++c4) {
            int ct = ph * 4 + c4;
            int col = c4 * 16 + lm;
#pragma unroll
            for (int reg = 0; reg < 4; ++reg) {
                float vL = accL[ct][reg], vH = accH[ct][reg];
                vL = __builtin_amdgcn_rcpf(1.f + __expf(-vL));
                vH = __builtin_amdgcn_rcpf(1.f + __expf(-vH));
                int row = lg * 4 + reg;
                myl[row * 68 + col] = vL;
                myl[(row + 16) * 68 + col] = vH;
            }
        }
        __syncthreads();                             // order LDS write -> read
        // drain: 8 instrs, each 64 lanes x 16B = 4 rows x 256B contiguous
#pragma unroll
        for (int i = 0; i < 8; ++i) {
            int row = i * 4 + lg;
            f32x4 v = *reinterpret_cast<const f32x4*>(&myl[row * 68 + lm * 4]);
            float* dst = &out[(size_t)(i0 + row) * NN + j0 + ph * 64 + lm * 4];
            __builtin_nontemporal_store(v, reinterpret_cast<f32x4*>(dst));
        }
        __syncthreads();                             // before next phase reuses LDS
    }
}

extern "C" void kernel_launch(void* const* d_in, const int* in_sizes, int n_in,
                              void* d_out, int out_size, void* d_ws, size_t ws_size,
                              hipStream_t stream) {
    const float* x     = (const float*)d_in[0];
    const int*   ei    = (const int*)d_in[1];
    // d_in[2] = adj (unused)
    const float* Wg    = (const float*)d_in[3];
    const float* att_s = (const float*)d_in[4];
    const float* att_d = (const float*)d_in[5];
    const float* bg    = (const float*)d_in[6];
    const float* W1    = (const float*)d_in[7];
    const float* b1    = (const float*)d_in[8];
    const float* W2    = (const float*)d_in[9];
    const float* b2    = (const float*)d_in[10];

    float* ws    = (float*)d_ws;
    float* a_src = ws;                              // NN
    float* a_dst = a_src + NN;                      // NN
    float* xtw   = a_dst + NN;                      // FD*EMB f32 [zero start]
    int*   deg   = (int*)(xtw + FD * EMB);          // NN [zeroed]
    int*   cursor= deg + NN;                        // NN [zeroed, end of range]
    int*   row_start = cursor + NN;                 // NN+4
    int*   ssrc  = row_start + NN + 4;              // NE
    __hip_bfloat16* xbf  = (__hip_bfloat16*)(ssrc + NE);       // NN*FD
    __hip_bfloat16* WgT  = xbf + (size_t)NN * FD;              // OD*FD
    __hip_bfloat16* hbf  = WgT + (size_t)OD * FD;              // NN*OD
    __hip_bfloat16* ebf  = hbf + (size_t)NN * OD;              // NN*OD
    __hip_bfloat16* h2bf = ebf + (size_t)NN * OD;              // FD*OD

    float* Ahat = (float*)d_out;
    float* Xhat = Ahat + (size_t)NN * NN;

    const int prep_blocks = 384 + NN * FD / 2048 + 1 + NE / 256;   // 6529
    k_prep<<<prep_blocks, 256, 0, stream>>>(x, xbf, Wg, WgT, ei, deg, (int*)xtw);
    k_scan<<<1, 256, 0, stream>>>(deg, row_start);
    k_scat_hmm<<<NE / 256 + NN / 64, 256, 0, stream>>>(ei, row_start, cursor, ssrc,
                                                       xbf, WgT, att_s, att_d,
                                                       hbf, a_src, a_dst);
    k_aggcsr<<<NN / 4, 256, 0, stream>>>(row_start, ssrc, a_src, a_dst,
                                         (const u16*)hbf, bg, ebf);
    k_xtw<<<256, 256, 0, stream>>>(x, W1, xtw);
    k_h2<<<FD / 4, 256, 0, stream>>>(xtw, b1, W2, b2, h2bf);
    k_mmX<<<dim3(NN / 128, FD / 64), 256, 0, stream>>>(ebf, h2bf, Xhat, FD);
    k_mmA<<<dim3(NN / 128, NN / 128), 256, 0, stream>>>(ebf, Ahat);
}

// Round 7
// 474.594 us; speedup vs baseline: 1.5839x; 1.0880x over previous
//
#include <hip/hip_runtime.h>
#include <hip/hip_bf16.h>

#define NN 16384     // nodes
#define FD 512       // feature dim
#define EMB 128      // embed_dim (dense1)
#define OD 64        // out_dim
#define NE 524288    // edges (self-loops handled analytically)

typedef __bf16 bf16x8 __attribute__((ext_vector_type(8)));
typedef float f32x4 __attribute__((ext_vector_type(4)));
typedef unsigned short u16;

__device__ inline float bfu2f(u16 u) {
    unsigned int x = (unsigned int)u << 16;
    float f;
    __builtin_memcpy(&f, &x, 4);
    return f;
}

// ===== prep: xtw partials (no atomics) | dst hist | x->bf16 | WgT ==========
__global__ __launch_bounds__(256) void k_prep(
    const float* __restrict__ x, __hip_bfloat16* __restrict__ xbf,
    const float* __restrict__ Wg, __hip_bfloat16* __restrict__ WgT,
    const int* __restrict__ ei, int* __restrict__ deg,
    const float* __restrict__ W1, float* __restrict__ part) {
    __shared__ float xs[4][64];
    __shared__ float wsh[4][EMB];
    int b = blockIdx.x;
    int t = threadIdx.x;
    if (b < 256) {                                   // xtw partial tile
        int fb = b & 7, nc = b >> 3;
        int f0 = fb * 64, nb = nc * 512;
        int eb = (t & 15) * 8;                       // 8 e per thread
        int fbase = (t >> 4) * 4;                    // 4 f per thread
        float acc[4][8] = {};
        for (int n4 = 0; n4 < 512; n4 += 4) {
            { int nn = t >> 6, ff = t & 63;
              xs[nn][ff] = x[(size_t)(nb + n4 + nn) * FD + f0 + ff]; }
#pragma unroll
            for (int j = 0; j < 2; ++j) {
                int idx = t + j * 256;
                wsh[idx >> 7][idx & 127] = W1[(size_t)(nb + n4 + (idx >> 7)) * EMB + (idx & 127)];
            }
            __syncthreads();
#pragma unroll
            for (int nn = 0; nn < 4; ++nn) {
                float xv[4], wv[8];
#pragma unroll
                for (int i = 0; i < 4; ++i) xv[i] = xs[nn][fbase + i];
#pragma unroll
                for (int j = 0; j < 8; ++j) wv[j] = wsh[nn][eb + j];
#pragma unroll
                for (int i = 0; i < 4; ++i)
#pragma unroll
                    for (int j = 0; j < 8; ++j) acc[i][j] += xv[i] * wv[j];
            }
            __syncthreads();
        }
#pragma unroll
        for (int i = 0; i < 4; ++i) {
            float* dst = &part[((size_t)nc * FD + f0 + fbase + i) * EMB + eb];
            *reinterpret_cast<f32x4*>(dst) = *reinterpret_cast<f32x4*>(&acc[i][0]);
            *reinterpret_cast<f32x4*>(dst + 4) = *reinterpret_cast<f32x4*>(&acc[i][4]);
        }
        return;
    }
    b -= 256;
    if (b < NE / 256) {                              // histogram of dst
        int i = b * 256 + t;
        atomicAdd(deg + ei[NE + i], 1);
        return;
    }
    b -= NE / 256;
    if (b < NN * FD / 2048) {                        // x -> bf16
        size_t i = ((size_t)b * 256 + t) * 8;
        float4 v0 = *reinterpret_cast<const float4*>(x + i);
        float4 v1 = *reinterpret_cast<const float4*>(x + i + 4);
        __hip_bfloat16 o[8];
        o[0] = __float2bfloat16(v0.x); o[1] = __float2bfloat16(v0.y);
        o[2] = __float2bfloat16(v0.z); o[3] = __float2bfloat16(v0.w);
        o[4] = __float2bfloat16(v1.x); o[5] = __float2bfloat16(v1.y);
        o[6] = __float2bfloat16(v1.z); o[7] = __float2bfloat16(v1.w);
        *reinterpret_cast<uint4*>(xbf + i) = *reinterpret_cast<const uint4*>(o);
        return;
    }
    b -= NN * FD / 2048;
    {                                                // WgT[c][k] = Wg[k][c]
        int c = t >> 2;
        int k0 = (t & 3) * 128;
        for (int j = 0; j < 128; ++j)
            WgT[c * 512 + k0 + j] = __float2bfloat16(Wg[(size_t)(k0 + j) * OD + c]);
    }
}

// ---------------- exclusive scan deg[NN] -> row_start (parallel) -----------
__global__ __launch_bounds__(256) void k_scan(const int* __restrict__ deg,
                                              int* __restrict__ row_start) {
    __shared__ int part[256];
    int t = threadIdx.x;
    int base = t * 64;                                   // NN/256 = 64
    int s = 0;
    for (int j = 0; j < 64; ++j) s += deg[base + j];
    part[t] = s;
    __syncthreads();
    for (int off = 1; off < 256; off <<= 1) {
        int v = (t >= off) ? part[t - off] : 0;
        __syncthreads();
        part[t] += v;
        __syncthreads();
    }
    int run = part[t] - s;                               // exclusive
    if (t == 255) row_start[NN] = part[255];
    for (int j = 0; j < 64; ++j) { row_start[base + j] = run; run += deg[base + j]; }
}

// ===== mid: CSR scatter | h = xbf@Wg MFMA + a_src/a_dst | h2 reduce ========
__global__ __launch_bounds__(256) void k_mid(
    const int* __restrict__ ei, const int* __restrict__ row_start,
    int* __restrict__ cursor, int* __restrict__ ssrc,
    const __hip_bfloat16* __restrict__ xbf, const __hip_bfloat16* __restrict__ WgT,
    const float* __restrict__ att_s, const float* __restrict__ att_d,
    __hip_bfloat16* __restrict__ hbf, float* __restrict__ a_src, float* __restrict__ a_dst,
    const float* __restrict__ part, const float* __restrict__ b1,
    const float* __restrict__ W2, const float* __restrict__ b2,
    __hip_bfloat16* __restrict__ h2bf) {
    __shared__ float hv[4][EMB];
    int b = blockIdx.x;
    int t = threadIdx.x;
    if (b < NE / 256) {                              // scatter
        int i = b * 256 + t;
        int d = ei[NE + i];
        int pos = atomicAdd(cursor + d, 1);
        ssrc[row_start[d] + pos] = ei[i];
        return;
    }
    b -= NE / 256;
    int w = t >> 6, l = t & 63;
    if (b < NN / 64) {                               // hmm MFMA, 64 rows/block
        int lg = l >> 4, lm = l & 15;
        int r0 = b * 64 + w * 16;
        const bf16x8* Xp = reinterpret_cast<const bf16x8*>(xbf);
        const bf16x8* Wp = reinterpret_cast<const bf16x8*>(WgT);
        bf16x8 a[16];
        size_t abase = (size_t)(r0 + lm) * 64 + lg;
#pragma unroll
        for (int kc = 0; kc < 16; ++kc) a[kc] = Xp[abase + kc * 4];
        f32x4 acc[4];
#pragma unroll
        for (int j = 0; j < 4; ++j) {
            f32x4 c = {0.f, 0.f, 0.f, 0.f};
            size_t bbase = (size_t)(j * 16 + lm) * 64 + lg;
#pragma unroll
            for (int kc = 0; kc < 16; ++kc)
                c = __builtin_amdgcn_mfma_f32_16x16x32_bf16(a[kc], Wp[bbase + kc * 4], c, 0, 0, 0);
            acc[j] = c;
        }
#pragma unroll
        for (int j = 0; j < 4; ++j)
#pragma unroll
            for (int reg = 0; reg < 4; ++reg)
                hbf[(size_t)(r0 + lg * 4 + reg) * OD + j * 16 + lm] = __float2bfloat16(acc[j][reg]);
        float ats0 = att_s[lm], ats1 = att_s[16 + lm], ats2 = att_s[32 + lm], ats3 = att_s[48 + lm];
        float atd0 = att_d[lm], atd1 = att_d[16 + lm], atd2 = att_d[32 + lm], atd3 = att_d[48 + lm];
#pragma unroll
        for (int reg = 0; reg < 4; ++reg) {
            float ps = acc[0][reg] * ats0 + acc[1][reg] * ats1 + acc[2][reg] * ats2 + acc[3][reg] * ats3;
            float pd = acc[0][reg] * atd0 + acc[1][reg] * atd1 + acc[2][reg] * atd2 + acc[3][reg] * atd3;
#pragma unroll
            for (int off = 1; off < 16; off <<= 1) {
                ps += __shfl_xor(ps, off, 64);
                pd += __shfl_xor(pd, off, 64);
            }
            if (lm == 0) {
                int r = r0 + lg * 4 + reg;
                a_src[r] = ps;
                a_dst[r] = pd;
            }
        }
        return;
    }
    b -= NN / 64;
    {                                                // h2: reduce partials
        int f = b * 4 + w;
        float s0 = 0.f, s1 = 0.f;
        for (int nc = 0; nc < 32; ++nc) {
            const float* p = part + ((size_t)nc * FD + f) * EMB;
            s0 += p[l];
            s1 += p[l + 64];
        }
        s0 += b1[l]; s1 += b1[l + 64];
        hv[w][l] = s0 > 0.f ? s0 : 0.f;
        hv[w][l + 64] = s1 > 0.f ? s1 : 0.f;
        __syncthreads();
        float acc = b2[l];
        const float* myhv = hv[w];
        for (int e = 0; e < EMB; ++e)
            acc += myhv[e] * W2[e * OD + l];
        h2bf[(size_t)f * OD + l] = __float2bfloat16(acc);
    }
}

// ------- fused softmax+aggregate+bias+leaky+bf16: one wave per dst node ----
__global__ __launch_bounds__(256) void k_aggcsr(
    const int* __restrict__ row_start, const int* __restrict__ ssrc,
    const float* __restrict__ a_src, const float* __restrict__ a_dst,
    const u16* __restrict__ hb, const float* __restrict__ bg,
    __hip_bfloat16* __restrict__ ebf) {
    int node = blockIdx.x * 4 + (threadIdx.x >> 6);
    int lane = threadIdx.x & 63;
    float ad = a_dst[node];
    float e0 = a_src[node] + ad;                 // self loop
    e0 = e0 > 0.f ? e0 : 0.5f * e0;
    float p0 = __expf(e0);
    float denom = p0;
    float acc = p0 * bfu2f(hb[(size_t)node * OD + lane]);
    int j0 = row_start[node], j1 = row_start[node + 1];
    int j = j0;
    for (; j + 2 <= j1; j += 2) {
        int sA = ssrc[j], sB = ssrc[j + 1];
        float hA = bfu2f(hb[(size_t)sA * OD + lane]);
        float hB = bfu2f(hb[(size_t)sB * OD + lane]);
        float eA = a_src[sA] + ad, eB = a_src[sB] + ad;
        eA = eA > 0.f ? eA : 0.5f * eA;
        eB = eB > 0.f ? eB : 0.5f * eB;
        float pA = __expf(eA), pB = __expf(eB);
        denom += pA + pB;
        acc += pA * hA + pB * hB;
    }
    if (j < j1) {
        int s = ssrc[j];
        float e = a_src[s] + ad;
        e = e > 0.f ? e : 0.5f * e;
        float pv = __expf(e);
        denom += pv;
        acc += pv * bfu2f(hb[(size_t)s * OD + lane]);
    }
    float v = acc * __builtin_amdgcn_rcpf(denom) + bg[lane];
    v = v > 0.f ? v : 0.01f * v;                 // embed leaky_relu 0.01
    ebf[(size_t)node * OD + lane] = __float2bfloat16(v);
}

// ===== out[i][j] = act(A_rows[i].B_rows[j]), K=64; LDS transpose epilogue ==
// LDS tile is PER-WAVE private: sync is wave-local lgkmcnt, no __syncthreads
// (avoids the vmcnt(0)-before-barrier drain of in-flight NT stores).
template <bool SIG>
__device__ __forceinline__ void mmT_body(const __hip_bfloat16* __restrict__ A,
                                         const __hip_bfloat16* __restrict__ B,
                                         float* __restrict__ out, int ldo,
                                         int bx, int by) {
    __shared__ float ls[4][32 * 68];                 // 34.8 KB, per-wave private
    int w = threadIdx.x >> 6, l = threadIdx.x & 63;
    int lg = l >> 4, lm = l & 15;
    int i0 = bx * 128 + w * 32;
    int j0 = by * 128;
    const bf16x8* Ap = reinterpret_cast<const bf16x8*>(A);
    const bf16x8* Bp = reinterpret_cast<const bf16x8*>(B);
    size_t arow = (size_t)(i0 + lm) * 8;             // row stride 64 bf16 = 8 chunks
    bf16x8 a0 = Ap[arow + lg];
    bf16x8 a1 = Ap[arow + 4 + lg];
    bf16x8 a2 = Ap[arow + 128 + lg];
    bf16x8 a3 = Ap[arow + 128 + 4 + lg];
    f32x4 accL[8], accH[8];
#pragma unroll
    for (int ct = 0; ct < 8; ++ct) {
        size_t brow = (size_t)(j0 + ct * 16 + lm) * 8;
        bf16x8 b0 = Bp[brow + lg];
        bf16x8 b1 = Bp[brow + 4 + lg];
        f32x4 cL = {0.f, 0.f, 0.f, 0.f};
        f32x4 cH = {0.f, 0.f, 0.f, 0.f};
        cL = __builtin_amdgcn_mfma_f32_16x16x32_bf16(a0, b0, cL, 0, 0, 0);
        cL = __builtin_amdgcn_mfma_f32_16x16x32_bf16(a1, b1, cL, 0, 0, 0);
        cH = __builtin_amdgcn_mfma_f32_16x16x32_bf16(a2, b0, cH, 0, 0, 0);
        cH = __builtin_amdgcn_mfma_f32_16x16x32_bf16(a3, b1, cH, 0, 0, 0);
        accL[ct] = cL;
        accH[ct] = cH;
    }
    float* myl = ls[w];
#pragma unroll
    for (int ph = 0; ph < 2; ++ph) {
        if (ph == 1) {                               // WAR: ph0 reads done
            asm volatile("s_waitcnt lgkmcnt(0)" ::: "memory");
            __builtin_amdgcn_sched_barrier(0);
        }
#pragma unroll
        for (int c4 = 0; c4 < 4; ++c4) {
            int ct = ph * 4 + c4;
            int col = c4 * 16 + lm;
#pragma unroll
            for (int reg = 0; reg < 4; ++reg) {
                float vL = accL[ct][reg], vH = accH[ct][reg];
                if (SIG) {
                    vL = __builtin_amdgcn_rcpf(1.f + __expf(-vL));
                    vH = __builtin_amdgcn_rcpf(1.f + __expf(-vH));
                }
                int row = lg * 4 + reg;
                myl[row * 68 + col] = vL;
                myl[(row + 16) * 68 + col] = vH;
            }
        }
        asm volatile("s_waitcnt lgkmcnt(0)" ::: "memory");   // RAW: writes done
        __builtin_amdgcn_sched_barrier(0);
#pragma unroll
        for (int i = 0; i < 8; ++i) {
            int row = i * 4 + lg;
            f32x4 v = *reinterpret_cast<const f32x4*>(&myl[row * 68 + lm * 4]);
            float* dst = &out[(size_t)(i0 + row) * ldo + j0 + ph * 64 + lm * 4];
            __builtin_nontemporal_store(v, reinterpret_cast<f32x4*>(dst));
        }
    }
}

__global__ __launch_bounds__(256) void k_mmX(const __hip_bfloat16* __restrict__ A,
                                             const __hip_bfloat16* __restrict__ B,
                                             float* __restrict__ out) {
    mmT_body<false>(A, B, out, FD, blockIdx.x, blockIdx.y);
}

__global__ __launch_bounds__(256) void k_mmA(const __hip_bfloat16* __restrict__ A,
                                             float* __restrict__ out) {
    mmT_body<true>(A, A, out, NN, blockIdx.x, blockIdx.y);
}

extern "C" void kernel_launch(void* const* d_in, const int* in_sizes, int n_in,
                              void* d_out, int out_size, void* d_ws, size_t ws_size,
                              hipStream_t stream) {
    const float* x     = (const float*)d_in[0];
    const int*   ei    = (const int*)d_in[1];
    // d_in[2] = adj (unused)
    const float* Wg    = (const float*)d_in[3];
    const float* att_s = (const float*)d_in[4];
    const float* att_d = (const float*)d_in[5];
    const float* bg    = (const float*)d_in[6];
    const float* W1    = (const float*)d_in[7];
    const float* b1    = (const float*)d_in[8];
    const float* W2    = (const float*)d_in[9];
    const float* b2    = (const float*)d_in[10];

    float* ws    = (float*)d_ws;
    float* a_src = ws;                              // NN
    float* a_dst = a_src + NN;                      // NN
    int*   deg   = (int*)(a_dst + NN);              // NN [memset 0]
    int*   cursor= deg + NN;                        // NN [memset 0]
    int*   row_start = cursor + NN;                 // NN+4
    int*   ssrc  = row_start + NN + 4;              // NE
    float* part  = (float*)(ssrc + NE);             // 32*FD*EMB = 2M f32
    __hip_bfloat16* xbf  = (__hip_bfloat16*)(part + 32 * FD * EMB); // NN*FD
    __hip_bfloat16* WgT  = xbf + (size_t)NN * FD;              // OD*FD
    __hip_bfloat16* hbf  = WgT + (size_t)OD * FD;              // NN*OD
    __hip_bfloat16* ebf  = hbf + (size_t)NN * OD;              // NN*OD
    __hip_bfloat16* h2bf = ebf + (size_t)NN * OD;              // FD*OD

    float* Ahat = (float*)d_out;
    float* Xhat = Ahat + (size_t)NN * NN;

    hipMemsetAsync(deg, 0, 2 * NN * sizeof(int), stream);
    const int prep_blocks = 256 + NE / 256 + NN * FD / 2048 + 1;   // 6401
    k_prep<<<prep_blocks, 256, 0, stream>>>(x, xbf, Wg, WgT, ei, deg, W1, part);
    k_scan<<<1, 256, 0, stream>>>(deg, row_start);
    const int mid_blocks = NE / 256 + NN / 64 + FD / 4;            // 2432
    k_mid<<<mid_blocks, 256, 0, stream>>>(ei, row_start, cursor, ssrc,
                                          xbf, WgT, att_s, att_d,
                                          hbf, a_src, a_dst,
                                          part, b1, W2, b2, h2bf);
    k_aggcsr<<<NN / 4, 256, 0, stream>>>(row_start, ssrc, a_src, a_dst,
                                         (const u16*)hbf, bg, ebf);
    k_mmX<<<dim3(NN / 128, FD / 128), 256, 0, stream>>>(ebf, h2bf, Xhat);
    k_mmA<<<dim3(NN / 128, NN / 128), 256, 0, stream>>>(ebf, Ahat);
}

// Round 8
// 409.076 us; speedup vs baseline: 1.8376x; 1.1602x over previous
//
#include <hip/hip_runtime.h>
#include <hip/hip_bf16.h>

#define NN 16384     // nodes
#define FD 512       // feature dim
#define EMB 128      // embed_dim (dense1)
#define OD 64        // out_dim
#define NE 524288    // edges (self-loops handled analytically)

typedef __bf16 bf16x8 __attribute__((ext_vector_type(8)));
typedef float f32x4 __attribute__((ext_vector_type(4)));
typedef unsigned short u16;

__device__ inline float bfu2f(u16 u) {
    unsigned int x = (unsigned int)u << 16;
    float f;
    __builtin_memcpy(&f, &x, 4);
    return f;
}

// ===== prep: xtw partials (no atomics) | dst hist | x->bf16 | WgT ==========
__global__ __launch_bounds__(256) void k_prep(
    const float* __restrict__ x, __hip_bfloat16* __restrict__ xbf,
    const float* __restrict__ Wg, __hip_bfloat16* __restrict__ WgT,
    const int* __restrict__ ei, int* __restrict__ deg,
    const float* __restrict__ W1, float* __restrict__ part) {
    __shared__ float xs[4][64];
    __shared__ float wsh[4][EMB];
    int b = blockIdx.x;
    int t = threadIdx.x;
    if (b < 256) {                                   // xtw partial tile
        int fb = b & 7, nc = b >> 3;
        int f0 = fb * 64, nb = nc * 512;
        int eb = (t & 15) * 8;                       // 8 e per thread
        int fbase = (t >> 4) * 4;                    // 4 f per thread
        float acc[4][8] = {};
        for (int n4 = 0; n4 < 512; n4 += 4) {
            { int nn = t >> 6, ff = t & 63;
              xs[nn][ff] = x[(size_t)(nb + n4 + nn) * FD + f0 + ff]; }
#pragma unroll
            for (int j = 0; j < 2; ++j) {
                int idx = t + j * 256;
                wsh[idx >> 7][idx & 127] = W1[(size_t)(nb + n4 + (idx >> 7)) * EMB + (idx & 127)];
            }
            __syncthreads();
#pragma unroll
            for (int nn = 0; nn < 4; ++nn) {
                float xv[4], wv[8];
#pragma unroll
                for (int i = 0; i < 4; ++i) xv[i] = xs[nn][fbase + i];
#pragma unroll
                for (int j = 0; j < 8; ++j) wv[j] = wsh[nn][eb + j];
#pragma unroll
                for (int i = 0; i < 4; ++i)
#pragma unroll
                    for (int j = 0; j < 8; ++j) acc[i][j] += xv[i] * wv[j];
            }
            __syncthreads();
        }
#pragma unroll
        for (int i = 0; i < 4; ++i) {
            float* dst = &part[((size_t)nc * FD + f0 + fbase + i) * EMB + eb];
            *reinterpret_cast<f32x4*>(dst) = *reinterpret_cast<f32x4*>(&acc[i][0]);
            *reinterpret_cast<f32x4*>(dst + 4) = *reinterpret_cast<f32x4*>(&acc[i][4]);
        }
        return;
    }
    b -= 256;
    if (b < NE / 256) {                              // histogram of dst
        int i = b * 256 + t;
        atomicAdd(deg + ei[NE + i], 1);
        return;
    }
    b -= NE / 256;
    if (b < NN * FD / 2048) {                        // x -> bf16
        size_t i = ((size_t)b * 256 + t) * 8;
        float4 v0 = *reinterpret_cast<const float4*>(x + i);
        float4 v1 = *reinterpret_cast<const float4*>(x + i + 4);
        __hip_bfloat16 o[8];
        o[0] = __float2bfloat16(v0.x); o[1] = __float2bfloat16(v0.y);
        o[2] = __float2bfloat16(v0.z); o[3] = __float2bfloat16(v0.w);
        o[4] = __float2bfloat16(v1.x); o[5] = __float2bfloat16(v1.y);
        o[6] = __float2bfloat16(v1.z); o[7] = __float2bfloat16(v1.w);
        *reinterpret_cast<uint4*>(xbf + i) = *reinterpret_cast<const uint4*>(o);
        return;
    }
    b -= NN * FD / 2048;
    {                                                // WgT[c][k] = Wg[k][c]
        int c = t >> 2;
        int k0 = (t & 3) * 128;
        for (int j = 0; j < 128; ++j)
            WgT[c * 512 + k0 + j] = __float2bfloat16(Wg[(size_t)(k0 + j) * OD + c]);
    }
}

// ---------------- exclusive scan deg[NN] -> row_start (parallel) -----------
__global__ __launch_bounds__(256) void k_scan(const int* __restrict__ deg,
                                              int* __restrict__ row_start) {
    __shared__ int part[256];
    int t = threadIdx.x;
    int base = t * 64;                                   // NN/256 = 64
    int s = 0;
    for (int j = 0; j < 64; ++j) s += deg[base + j];
    part[t] = s;
    __syncthreads();
    for (int off = 1; off < 256; off <<= 1) {
        int v = (t >= off) ? part[t - off] : 0;
        __syncthreads();
        part[t] += v;
        __syncthreads();
    }
    int run = part[t] - s;                               // exclusive
    if (t == 255) row_start[NN] = part[255];
    for (int j = 0; j < 64; ++j) { row_start[base + j] = run; run += deg[base + j]; }
}

// ===== mid: CSR scatter | h = xbf@Wg MFMA + a_src/a_dst | h2 reduce ========
__global__ __launch_bounds__(256) void k_mid(
    const int* __restrict__ ei, const int* __restrict__ row_start,
    int* __restrict__ cursor, int* __restrict__ ssrc,
    const __hip_bfloat16* __restrict__ xbf, const __hip_bfloat16* __restrict__ WgT,
    const float* __restrict__ att_s, const float* __restrict__ att_d,
    __hip_bfloat16* __restrict__ hbf, float* __restrict__ a_src, float* __restrict__ a_dst,
    const float* __restrict__ part, const float* __restrict__ b1,
    const float* __restrict__ W2, const float* __restrict__ b2,
    __hip_bfloat16* __restrict__ h2bf) {
    __shared__ float hv[4][EMB];
    int b = blockIdx.x;
    int t = threadIdx.x;
    if (b < NE / 256) {                              // scatter
        int i = b * 256 + t;
        int d = ei[NE + i];
        int pos = atomicAdd(cursor + d, 1);
        ssrc[row_start[d] + pos] = ei[i];
        return;
    }
    b -= NE / 256;
    int w = t >> 6, l = t & 63;
    if (b < NN / 64) {                               // hmm MFMA, 64 rows/block
        int lg = l >> 4, lm = l & 15;
        int r0 = b * 64 + w * 16;
        const bf16x8* Xp = reinterpret_cast<const bf16x8*>(xbf);
        const bf16x8* Wp = reinterpret_cast<const bf16x8*>(WgT);
        bf16x8 a[16];
        size_t abase = (size_t)(r0 + lm) * 64 + lg;
#pragma unroll
        for (int kc = 0; kc < 16; ++kc) a[kc] = Xp[abase + kc * 4];
        f32x4 acc[4];
#pragma unroll
        for (int j = 0; j < 4; ++j) {
            f32x4 c = {0.f, 0.f, 0.f, 0.f};
            size_t bbase = (size_t)(j * 16 + lm) * 64 + lg;
#pragma unroll
            for (int kc = 0; kc < 16; ++kc)
                c = __builtin_amdgcn_mfma_f32_16x16x32_bf16(a[kc], Wp[bbase + kc * 4], c, 0, 0, 0);
            acc[j] = c;
        }
#pragma unroll
        for (int j = 0; j < 4; ++j)
#pragma unroll
            for (int reg = 0; reg < 4; ++reg)
                hbf[(size_t)(r0 + lg * 4 + reg) * OD + j * 16 + lm] = __float2bfloat16(acc[j][reg]);
        float ats0 = att_s[lm], ats1 = att_s[16 + lm], ats2 = att_s[32 + lm], ats3 = att_s[48 + lm];
        float atd0 = att_d[lm], atd1 = att_d[16 + lm], atd2 = att_d[32 + lm], atd3 = att_d[48 + lm];
#pragma unroll
        for (int reg = 0; reg < 4; ++reg) {
            float ps = acc[0][reg] * ats0 + acc[1][reg] * ats1 + acc[2][reg] * ats2 + acc[3][reg] * ats3;
            float pd = acc[0][reg] * atd0 + acc[1][reg] * atd1 + acc[2][reg] * atd2 + acc[3][reg] * atd3;
#pragma unroll
            for (int off = 1; off < 16; off <<= 1) {
                ps += __shfl_xor(ps, off, 64);
                pd += __shfl_xor(pd, off, 64);
            }
            if (lm == 0) {
                int r = r0 + lg * 4 + reg;
                a_src[r] = ps;
                a_dst[r] = pd;
            }
        }
        return;
    }
    b -= NN / 64;
    {                                                // h2: reduce partials
        int f = b * 4 + w;
        float s0 = 0.f, s1 = 0.f;
        for (int nc = 0; nc < 32; ++nc) {
            const float* p = part + ((size_t)nc * FD + f) * EMB;
            s0 += p[l];
            s1 += p[l + 64];
        }
        s0 += b1[l]; s1 += b1[l + 64];
        hv[w][l] = s0 > 0.f ? s0 : 0.f;
        hv[w][l + 64] = s1 > 0.f ? s1 : 0.f;
        __syncthreads();
        float acc = b2[l];
        const float* myhv = hv[w];
        for (int e = 0; e < EMB; ++e)
            acc += myhv[e] * W2[e * OD + l];
        h2bf[(size_t)f * OD + l] = __float2bfloat16(acc);
    }
}

// ------- fused softmax+aggregate+bias+leaky+bf16: one wave per dst node ----
__global__ __launch_bounds__(256) void k_aggcsr(
    const int* __restrict__ row_start, const int* __restrict__ ssrc,
    const float* __restrict__ a_src, const float* __restrict__ a_dst,
    const u16* __restrict__ hb, const float* __restrict__ bg,
    __hip_bfloat16* __restrict__ ebf) {
    int node = blockIdx.x * 4 + (threadIdx.x >> 6);
    int lane = threadIdx.x & 63;
    float ad = a_dst[node];
    float e0 = a_src[node] + ad;                 // self loop
    e0 = e0 > 0.f ? e0 : 0.5f * e0;
    float p0 = __expf(e0);
    float denom = p0;
    float acc = p0 * bfu2f(hb[(size_t)node * OD + lane]);
    int j0 = row_start[node], j1 = row_start[node + 1];
    int j = j0;
    for (; j + 2 <= j1; j += 2) {
        int sA = ssrc[j], sB = ssrc[j + 1];
        float hA = bfu2f(hb[(size_t)sA * OD + lane]);
        float hB = bfu2f(hb[(size_t)sB * OD + lane]);
        float eA = a_src[sA] + ad, eB = a_src[sB] + ad;
        eA = eA > 0.f ? eA : 0.5f * eA;
        eB = eB > 0.f ? eB : 0.5f * eB;
        float pA = __expf(eA), pB = __expf(eB);
        denom += pA + pB;
        acc += pA * hA + pB * hB;
    }
    if (j < j1) {
        int s = ssrc[j];
        float e = a_src[s] + ad;
        e = e > 0.f ? e : 0.5f * e;
        float pv = __expf(e);
        denom += pv;
        acc += pv * bfu2f(hb[(size_t)s * OD + lane]);
    }
    float v = acc * __builtin_amdgcn_rcpf(denom) + bg[lane];
    v = v > 0.f ? v : 0.01f * v;                 // embed leaky_relu 0.01
    ebf[(size_t)node * OD + lane] = __float2bfloat16(v);
}

// ===== out[i][j] = act(A_rows[i].B_rows[j]), K=64; LDS transpose epilogue ==
// LDS tile per-wave private; wave-local lgkmcnt sync (no __syncthreads).
// rowT/colT passed explicitly: callers map blockIdx so CONSECUTIVE blocks
// share the row range and march columns (dense DRAM-page write locality).
template <bool SIG>
__device__ __forceinline__ void mmT_body(const __hip_bfloat16* __restrict__ A,
                                         const __hip_bfloat16* __restrict__ B,
                                         float* __restrict__ out, int ldo,
                                         int rowT, int colT) {
    __shared__ float ls[4][32 * 68];                 // 34.8 KB, per-wave private
    int w = threadIdx.x >> 6, l = threadIdx.x & 63;
    int lg = l >> 4, lm = l & 15;
    int i0 = rowT * 128 + w * 32;
    int j0 = colT * 128;
    const bf16x8* Ap = reinterpret_cast<const bf16x8*>(A);
    const bf16x8* Bp = reinterpret_cast<const bf16x8*>(B);
    size_t arow = (size_t)(i0 + lm) * 8;             // row stride 64 bf16 = 8 chunks
    bf16x8 a0 = Ap[arow + lg];
    bf16x8 a1 = Ap[arow + 4 + lg];
    bf16x8 a2 = Ap[arow + 128 + lg];
    bf16x8 a3 = Ap[arow + 128 + 4 + lg];
    f32x4 accL[8], accH[8];
#pragma unroll
    for (int ct = 0; ct < 8; ++ct) {
        size_t brow = (size_t)(j0 + ct * 16 + lm) * 8;
        bf16x8 b0 = Bp[brow + lg];
        bf16x8 b1 = Bp[brow + 4 + lg];
        f32x4 cL = {0.f, 0.f, 0.f, 0.f};
        f32x4 cH = {0.f, 0.f, 0.f, 0.f};
        cL = __builtin_amdgcn_mfma_f32_16x16x32_bf16(a0, b0, cL, 0, 0, 0);
        cL = __builtin_amdgcn_mfma_f32_16x16x32_bf16(a1, b1, cL, 0, 0, 0);
        cH = __builtin_amdgcn_mfma_f32_16x16x32_bf16(a2, b0, cH, 0, 0, 0);
        cH = __builtin_amdgcn_mfma_f32_16x16x32_bf16(a3, b1, cH, 0, 0, 0);
        accL[ct] = cL;
        accH[ct] = cH;
    }
    float* myl = ls[w];
#pragma unroll
    for (int ph = 0; ph < 2; ++ph) {
        if (ph == 1) {                               // WAR: ph0 reads done
            asm volatile("s_waitcnt lgkmcnt(0)" ::: "memory");
            __builtin_amdgcn_sched_barrier(0);
        }
#pragma unroll
        for (int c4 = 0; c4 < 4; ++c4) {
            int ct = ph * 4 + c4;
            int col = c4 * 16 + lm;
#pragma unroll
            for (int reg = 0; reg < 4; ++reg) {
                float vL = accL[ct][reg], vH = accH[ct][reg];
                if (SIG) {
                    vL = __builtin_amdgcn_rcpf(1.f + __expf(-vL));
                    vH = __builtin_amdgcn_rcpf(1.f + __expf(-vH));
                }
                int row = lg * 4 + reg;
                myl[row * 68 + col] = vL;
                myl[(row + 16) * 68 + col] = vH;
            }
        }
        asm volatile("s_waitcnt lgkmcnt(0)" ::: "memory");   // RAW: writes done
        __builtin_amdgcn_sched_barrier(0);
#pragma unroll
        for (int i = 0; i < 8; ++i) {
            int row = i * 4 + lg;
            f32x4 v = *reinterpret_cast<const f32x4*>(&myl[row * 68 + lm * 4]);
            float* dst = &out[(size_t)(i0 + row) * ldo + j0 + ph * 64 + lm * 4];
            __builtin_nontemporal_store(v, reinterpret_cast<f32x4*>(dst));
        }
    }
}

// blockIdx.x = COLUMN tile (fast-varying), blockIdx.y = ROW tile.
__global__ __launch_bounds__(256) void k_mmX(const __hip_bfloat16* __restrict__ A,
                                             const __hip_bfloat16* __restrict__ B,
                                             float* __restrict__ out) {
    mmT_body<false>(A, B, out, FD, blockIdx.y, blockIdx.x);
}

__global__ __launch_bounds__(256) void k_mmA(const __hip_bfloat16* __restrict__ A,
                                             float* __restrict__ out) {
    mmT_body<true>(A, A, out, NN, blockIdx.y, blockIdx.x);
}

extern "C" void kernel_launch(void* const* d_in, const int* in_sizes, int n_in,
                              void* d_out, int out_size, void* d_ws, size_t ws_size,
                              hipStream_t stream) {
    const float* x     = (const float*)d_in[0];
    const int*   ei    = (const int*)d_in[1];
    // d_in[2] = adj (unused)
    const float* Wg    = (const float*)d_in[3];
    const float* att_s = (const float*)d_in[4];
    const float* att_d = (const float*)d_in[5];
    const float* bg    = (const float*)d_in[6];
    const float* W1    = (const float*)d_in[7];
    const float* b1    = (const float*)d_in[8];
    const float* W2    = (const float*)d_in[9];
    const float* b2    = (const float*)d_in[10];

    float* ws    = (float*)d_ws;
    float* a_src = ws;                              // NN
    float* a_dst = a_src + NN;                      // NN
    int*   deg   = (int*)(a_dst + NN);              // NN [memset 0]
    int*   cursor= deg + NN;                        // NN [memset 0]
    int*   row_start = cursor + NN;                 // NN+4
    int*   ssrc  = row_start + NN + 4;              // NE
    float* part  = (float*)(ssrc + NE);             // 32*FD*EMB = 2M f32
    __hip_bfloat16* xbf  = (__hip_bfloat16*)(part + 32 * FD * EMB); // NN*FD
    __hip_bfloat16* WgT  = xbf + (size_t)NN * FD;              // OD*FD
    __hip_bfloat16* hbf  = WgT + (size_t)OD * FD;              // NN*OD
    __hip_bfloat16* ebf  = hbf + (size_t)NN * OD;              // NN*OD
    __hip_bfloat16* h2bf = ebf + (size_t)NN * OD;              // FD*OD

    float* Ahat = (float*)d_out;
    float* Xhat = Ahat + (size_t)NN * NN;

    hipMemsetAsync(deg, 0, 2 * NN * sizeof(int), stream);
    const int prep_blocks = 256 + NE / 256 + NN * FD / 2048 + 1;   // 6401
    k_prep<<<prep_blocks, 256, 0, stream>>>(x, xbf, Wg, WgT, ei, deg, W1, part);
    k_scan<<<1, 256, 0, stream>>>(deg, row_start);
    const int mid_blocks = NE / 256 + NN / 64 + FD / 4;            // 2432
    k_mid<<<mid_blocks, 256, 0, stream>>>(ei, row_start, cursor, ssrc,
                                          xbf, WgT, att_s, att_d,
                                          hbf, a_src, a_dst,
                                          part, b1, W2, b2, h2bf);
    k_aggcsr<<<NN / 4, 256, 0, stream>>>(row_start, ssrc, a_src, a_dst,
                                         (const u16*)hbf, bg, ebf);
    k_mmX<<<dim3(FD / 128, NN / 128), 256, 0, stream>>>(ebf, h2bf, Xhat);
    k_mmA<<<dim3(NN / 128, NN / 128), 256, 0, stream>>>(ebf, Ahat);
}